// Round 2
// baseline (179.013 us; speedup 1.0000x reference)
//
#include <hip/hip_runtime.h>
#include <math.h>

// Problem dims (fixed by reference)
constexpr int D   = 256;   // state dim
constexpr int D2  = 128;   // hidden 1
constexpr int D4  = 64;    // hidden 2 / node feature dim
constexpr int NN  = 64;    // MAX_NODES

// ---- Kernel A LDS layout (floats), dynamic shared ----
constexpr int XT_S   = 68;                       // Xt [256][68]  (x-tile transposed [k][n])
constexpr int H1_S   = 68;                       // H1t [128][68] (h1 transposed [c][n])
constexpr int HS_S   = 68;                       // Hs  [64][68]  (h row-major [n][c])
constexpr int NF_S   = 68;                       // NFs [64][68]  (nf transposed [c][n])
constexpr int WCAT_S = 196;                      // Wcat [64][196]
constexpr int OFF_XT   = 0;
constexpr int OFF_WC   = 256 * XT_S;             // 17408 ; W1 chunk [64][128] / W2 [128][64]
constexpr int OFF_H1T  = OFF_WC + 64 * 128;      // 25600
constexpr int LDS_FLOATS = OFF_H1T + 128 * H1_S; // 34304 floats = 137216 B
constexpr int OFF_HS   = 0;                      // aliases dead Xt region
constexpr int OFF_NFS  = 64 * HS_S;              // 4352 (still inside Xt region)
constexpr int OFF_WCAT = OFF_WC;                 // aliases dead Wc+H1t region

__global__ __launch_bounds__(256)
void kernelA(const float* __restrict__ x,
             const float* __restrict__ W1, const float* __restrict__ b1,
             const float* __restrict__ W2, const float* __restrict__ b2,
             const float* __restrict__ gamma, const float* __restrict__ beta,
             const float* __restrict__ E1, const float* __restrict__ S1,
             float* __restrict__ out_nf,
             float* __restrict__ ws_ei, float* __restrict__ ws_ej,
             float* __restrict__ ws_si, float* __restrict__ ws_sj)
{
    extern __shared__ float lds[];
    const int t = threadIdx.x;
    const int b = blockIdx.x;
    const int w = t >> 6, l = t & 63, g = l >> 3, m = l & 7;

    // ---- load x-tile transposed: Xt[k][n] = state[b][idx[n]][k] ----
    {
        const int n = t >> 2;
        // replicate jnp.linspace(0,127,64,f32).astype(int32): endpoint pinned
        const int srow = (n == 63) ? 127 : (int)((float)n * (127.0f / 63.0f));
        const float* src = x + ((size_t)b * 128 + srow) * D;
        const int c4b = (t & 3) * 16;
#pragma unroll
        for (int i = 0; i < 16; ++i) {
            const int k = 4 * (c4b + i);
            const float4 v = *(const float4*)(src + k);
            lds[OFF_XT + (k + 0) * XT_S + n] = v.x;
            lds[OFF_XT + (k + 1) * XT_S + n] = v.y;
            lds[OFF_XT + (k + 2) * XT_S + n] = v.z;
            lds[OFF_XT + (k + 3) * XT_S + n] = v.w;
        }
    }

    // ---- phase 2: h1 = relu(x @ W1 + b1)  (64 rows x 128 cols, K=256) ----
    float acc[8][4];
#pragma unroll
    for (int r = 0; r < 8; ++r) { acc[r][0]=0.f; acc[r][1]=0.f; acc[r][2]=0.f; acc[r][3]=0.f; }
    const int c0 = 32 * w + 4 * m;     // this thread's 4 output cols
    for (int ch = 0; ch < 4; ++ch) {
        __syncthreads();
        // stage W1 chunk rows [64ch, 64ch+64) -> Wc[64][128]
#pragma unroll
        for (int i = 0; i < 8; ++i) {
            const int f = t + 256 * i;               // 2048 float4
            const int kk = f >> 5, col4 = (f & 31) * 4;
            *(float4*)&lds[OFF_WC + kk * 128 + col4] =
                *(const float4*)(W1 + (size_t)(ch * 64 + kk) * D2 + col4);
        }
        __syncthreads();
        for (int kk = 0; kk < 64; ++kk) {
            const float4 xa = *(const float4*)&lds[OFF_XT + (ch * 64 + kk) * XT_S + 8 * g];
            const float4 xb = *(const float4*)&lds[OFF_XT + (ch * 64 + kk) * XT_S + 8 * g + 4];
            const float4 wv = *(const float4*)&lds[OFF_WC + kk * 128 + c0];
            const float xr[8] = {xa.x, xa.y, xa.z, xa.w, xb.x, xb.y, xb.z, xb.w};
            const float wc[4] = {wv.x, wv.y, wv.z, wv.w};
#pragma unroll
            for (int r = 0; r < 8; ++r)
#pragma unroll
                for (int c = 0; c < 4; ++c)
                    acc[r][c] = fmaf(xr[r], wc[c], acc[r][c]);
        }
    }
    // write h1 transposed to H1t[c][n] with relu + b1
    {
        const float4 b1v = *(const float4*)(b1 + c0);
        const float bb4[4] = {b1v.x, b1v.y, b1v.z, b1v.w};
#pragma unroll
        for (int c = 0; c < 4; ++c) {
            float4 lo, hi;
            lo.x = fmaxf(acc[0][c] + bb4[c], 0.f); lo.y = fmaxf(acc[1][c] + bb4[c], 0.f);
            lo.z = fmaxf(acc[2][c] + bb4[c], 0.f); lo.w = fmaxf(acc[3][c] + bb4[c], 0.f);
            hi.x = fmaxf(acc[4][c] + bb4[c], 0.f); hi.y = fmaxf(acc[5][c] + bb4[c], 0.f);
            hi.z = fmaxf(acc[6][c] + bb4[c], 0.f); hi.w = fmaxf(acc[7][c] + bb4[c], 0.f);
            *(float4*)&lds[OFF_H1T + (c0 + c) * H1_S + 8 * g]     = lo;
            *(float4*)&lds[OFF_H1T + (c0 + c) * H1_S + 8 * g + 4] = hi;
        }
    }
    __syncthreads();
    // stage W2 [128][64] into Wc region
#pragma unroll
    for (int i = 0; i < 8; ++i) {
        const int f = t + 256 * i;                   // 2048 float4
        const int kk = f >> 4, col4 = (f & 15) * 4;
        *(float4*)&lds[OFF_WC + kk * 64 + col4] =
            *(const float4*)(W2 + (size_t)kk * D4 + col4);
    }
    __syncthreads();

    // ---- phase 3: h = h1 @ W2 + b2 (64x64, K=128) ----
    float acc3[8][2];
#pragma unroll
    for (int r = 0; r < 8; ++r) { acc3[r][0] = 0.f; acc3[r][1] = 0.f; }
    const int c3 = 16 * w + 2 * m;
    for (int kk = 0; kk < 128; ++kk) {
        const float4 ha = *(const float4*)&lds[OFF_H1T + kk * H1_S + 8 * g];
        const float4 hb = *(const float4*)&lds[OFF_H1T + kk * H1_S + 8 * g + 4];
        const float2 wv = *(const float2*)&lds[OFF_WC + kk * 64 + c3];
        const float hr[8] = {ha.x, ha.y, ha.z, ha.w, hb.x, hb.y, hb.z, hb.w};
#pragma unroll
        for (int r = 0; r < 8; ++r) {
            acc3[r][0] = fmaf(hr[r], wv.x, acc3[r][0]);
            acc3[r][1] = fmaf(hr[r], wv.y, acc3[r][1]);
        }
    }
    {
        const float2 b2v = *(const float2*)(b2 + c3);
#pragma unroll
        for (int r = 0; r < 8; ++r) {
            float2 hv; hv.x = acc3[r][0] + b2v.x; hv.y = acc3[r][1] + b2v.y;
            *(float2*)&lds[OFF_HS + (8 * g + r) * HS_S + c3] = hv;   // Hs row-major
        }
    }
    __syncthreads();   // Hs complete; Wc/H1t now dead

    // ---- stage Wcat [64][196] = [E1a | E1b | S1a | S1b] (contraction k = nf col) ----
#pragma unroll
    for (int i = 0; i < 4; ++i) {  // E1 rows 0..63 -> cols [0,64)
        const int f = t + 256 * i; const int k = f >> 4, c4 = (f & 15) * 4;
        *(float4*)&lds[OFF_WCAT + k * WCAT_S + c4] = *(const float4*)(E1 + (size_t)k * D4 + c4);
    }
#pragma unroll
    for (int i = 0; i < 4; ++i) {  // E1 rows 64..127 -> cols [64,128)
        const int f = t + 256 * i; const int k = f >> 4, c4 = (f & 15) * 4;
        *(float4*)&lds[OFF_WCAT + k * WCAT_S + 64 + c4] = *(const float4*)(E1 + (size_t)(64 + k) * D4 + c4);
    }
#pragma unroll
    for (int i = 0; i < 2; ++i) {  // S1 rows 0..63 -> cols [128,160)
        const int f = t + 256 * i; const int k = f >> 3, c4 = (f & 7) * 4;
        *(float4*)&lds[OFF_WCAT + k * WCAT_S + 128 + c4] = *(const float4*)(S1 + (size_t)k * 32 + c4);
    }
#pragma unroll
    for (int i = 0; i < 2; ++i) {  // S1 rows 64..127 -> cols [160,192)
        const int f = t + 256 * i; const int k = f >> 3, c4 = (f & 7) * 4;
        *(float4*)&lds[OFF_WCAT + k * WCAT_S + 160 + c4] = *(const float4*)(S1 + (size_t)(64 + k) * 32 + c4);
    }

    // ---- phase 4: LayerNorm per row (two-pass, matches reference) ----
    {
        const int r4 = t >> 2, q = t & 3;   // 4 lanes per row, 16 cols each
        float vb[16];
        float s = 0.f;
#pragma unroll
        for (int d = 0; d < 4; ++d) {
            const float4 v = *(const float4*)&lds[OFF_HS + r4 * HS_S + 16 * q + 4 * d];
            vb[4*d+0] = v.x; vb[4*d+1] = v.y; vb[4*d+2] = v.z; vb[4*d+3] = v.w;
            s += v.x + v.y + v.z + v.w;
        }
        s += __shfl_xor(s, 1); s += __shfl_xor(s, 2);
        const float mu = s * (1.0f / 64.0f);
        float vs = 0.f;
#pragma unroll
        for (int e = 0; e < 16; ++e) { const float dd = vb[e] - mu; vs = fmaf(dd, dd, vs); }
        vs += __shfl_xor(vs, 1); vs += __shfl_xor(vs, 2);
        const float rstd = rsqrtf(vs * (1.0f / 64.0f) + 1e-5f);
#pragma unroll
        for (int d = 0; d < 4; ++d) {
            const float4 gv = *(const float4*)(gamma + 16 * q + 4 * d);
            const float4 bv = *(const float4*)(beta  + 16 * q + 4 * d);
            float4 o;
            o.x = fmaf((vb[4*d+0] - mu) * rstd, gv.x, bv.x);
            o.y = fmaf((vb[4*d+1] - mu) * rstd, gv.y, bv.y);
            o.z = fmaf((vb[4*d+2] - mu) * rstd, gv.z, bv.z);
            o.w = fmaf((vb[4*d+3] - mu) * rstd, gv.w, bv.w);
            *(float4*)(out_nf + (size_t)b * 4096 + (size_t)r4 * 64 + 16 * q + 4 * d) = o;
            // transposed copy for phase 5
            lds[OFF_NFS + (16*q + 4*d + 0) * NF_S + r4] = o.x;
            lds[OFF_NFS + (16*q + 4*d + 1) * NF_S + r4] = o.y;
            lds[OFF_NFS + (16*q + 4*d + 2) * NF_S + r4] = o.z;
            lds[OFF_NFS + (16*q + 4*d + 3) * NF_S + r4] = o.w;
        }
    }
    __syncthreads();

    // ---- phase 5: [ei|ej|si|sj] = nf @ Wcat  (64 x 192, K=64) ----
    float a5[8][6];
#pragma unroll
    for (int r = 0; r < 8; ++r)
#pragma unroll
        for (int c = 0; c < 6; ++c) a5[r][c] = 0.f;
    const int c5 = 48 * w + 6 * m;
    for (int kk = 0; kk < 64; ++kk) {
        const float4 na = *(const float4*)&lds[OFF_NFS + kk * NF_S + 8 * g];
        const float4 nb = *(const float4*)&lds[OFF_NFS + kk * NF_S + 8 * g + 4];
        const float2 w01 = *(const float2*)&lds[OFF_WCAT + kk * WCAT_S + c5];
        const float2 w23 = *(const float2*)&lds[OFF_WCAT + kk * WCAT_S + c5 + 2];
        const float2 w45 = *(const float2*)&lds[OFF_WCAT + kk * WCAT_S + c5 + 4];
        const float nr[8] = {na.x, na.y, na.z, na.w, nb.x, nb.y, nb.z, nb.w};
        const float wr[6] = {w01.x, w01.y, w23.x, w23.y, w45.x, w45.y};
#pragma unroll
        for (int r = 0; r < 8; ++r)
#pragma unroll
            for (int c = 0; c < 6; ++c)
                a5[r][c] = fmaf(nr[r], wr[c], a5[r][c]);
    }
    // scatter to workspace
#pragma unroll
    for (int cc = 0; cc < 6; ++cc) {
        const int c = c5 + cc;
        float* dst;
        int rs;
        if (c < 64)       { dst = ws_ei + (size_t)b * 4096 + c;        rs = 64; }
        else if (c < 128) { dst = ws_ej + (size_t)b * 4096 + (c - 64); rs = 64; }
        else if (c < 160) { dst = ws_si + (size_t)b * 2048 + (c - 128); rs = 32; }
        else              { dst = ws_sj + (size_t)b * 2048 + (c - 160); rs = 32; }
#pragma unroll
        for (int r = 0; r < 8; ++r)
            dst[(size_t)(8 * g + r) * rs] = a5[r][cc];
    }
}

// ---- Kernel B: per (b, i-quadrant) edge/strength MLP over 16x64 pairs ----
__global__ __launch_bounds__(256, 2)
void kernelB(const float* __restrict__ ws_ei, const float* __restrict__ ws_ej,
             const float* __restrict__ ws_si, const float* __restrict__ ws_sj,
             const float* __restrict__ bE1, const float* __restrict__ E2,
             const float* __restrict__ bE2, const float* __restrict__ E3,
             const float* __restrict__ bE3, const float* __restrict__ bS1,
             const float* __restrict__ S2, const float* __restrict__ bS2,
             float* __restrict__ out_adj, float* __restrict__ out_str)
{
    __shared__ float eisT[64 * 18];   // [h][i_local], bE1 folded
    __shared__ float ejT [64 * 66];   // [h][j]
    __shared__ float siT [32 * 18];   // [k][i_local], bS1 folded
    __shared__ float sjT [32 * 66];   // [k][j]
    __shared__ float e2s [64 * 32];   // E2 row-major
    __shared__ float E3s[32], S2s[32], bE2s[32];

    const int t  = threadIdx.x;
    const int qi = blockIdx.x;        // i-quadrant 0..3
    const int b  = blockIdx.y;        // batch 0..255

#pragma unroll
    for (int i = 0; i < 4; ++i) {     // eisT: 1024
        const int f = t + 256 * i; const int r = f >> 6, h = f & 63;
        eisT[h * 18 + r] = ws_ei[(size_t)b * 4096 + (size_t)(qi * 16 + r) * 64 + h] + bE1[h];
    }
#pragma unroll
    for (int i = 0; i < 16; ++i) {    // ejT: 4096
        const int f = t + 256 * i; const int r = f >> 6, h = f & 63;
        ejT[h * 66 + r] = ws_ej[(size_t)b * 4096 + (size_t)r * 64 + h];
    }
#pragma unroll
    for (int i = 0; i < 2; ++i) {     // siT: 512
        const int f = t + 256 * i; const int r = f >> 5, k = f & 31;
        siT[k * 18 + r] = ws_si[(size_t)b * 2048 + (size_t)(qi * 16 + r) * 32 + k] + bS1[k];
    }
#pragma unroll
    for (int i = 0; i < 8; ++i) {     // sjT: 2048
        const int f = t + 256 * i; const int r = f >> 5, k = f & 31;
        sjT[k * 66 + r] = ws_sj[(size_t)b * 2048 + (size_t)r * 32 + k];
    }
#pragma unroll
    for (int i = 0; i < 2; ++i) {     // e2s: 512 float4
        const int f4 = t + 256 * i;
        ((float4*)e2s)[f4] = ((const float4*)E2)[f4];
    }
    if (t < 32) { E3s[t] = E3[t]; S2s[t] = S2[t]; bE2s[t] = bE2[t]; }
    __syncthreads();

    const int jg = t & 31, ig = t >> 5;
    const int i0 = 2 * ig, j0 = 2 * jg;     // 2x2 pair tile

    float acc[4][32];
#pragma unroll
    for (int p = 0; p < 4; ++p)
#pragma unroll
        for (int k = 0; k < 32; ++k) acc[p][k] = 0.f;

    for (int h = 0; h < 64; ++h) {
        const float2 ea = *(const float2*)&eisT[h * 18 + i0];
        const float2 eb = *(const float2*)&ejT [h * 66 + j0];
        const float he00 = fmaxf(ea.x + eb.x, 0.f);
        const float he01 = fmaxf(ea.x + eb.y, 0.f);
        const float he10 = fmaxf(ea.y + eb.x, 0.f);
        const float he11 = fmaxf(ea.y + eb.y, 0.f);
#pragma unroll
        for (int k8 = 0; k8 < 8; ++k8) {
            const float4 e2v = *(const float4*)&e2s[h * 32 + 4 * k8];
            const float ev[4] = {e2v.x, e2v.y, e2v.z, e2v.w};
#pragma unroll
            for (int d = 0; d < 4; ++d) {
                acc[0][4*k8+d] = fmaf(he00, ev[d], acc[0][4*k8+d]);
                acc[1][4*k8+d] = fmaf(he01, ev[d], acc[1][4*k8+d]);
                acc[2][4*k8+d] = fmaf(he10, ev[d], acc[2][4*k8+d]);
                acc[3][4*k8+d] = fmaf(he11, ev[d], acc[3][4*k8+d]);
            }
        }
    }

    const float bE3v = bE3[0], bS2v = bS2[0];
    float prob[4];
#pragma unroll
    for (int p = 0; p < 4; ++p) {
        float dot = 0.f;
#pragma unroll
        for (int k = 0; k < 32; ++k)
            dot = fmaf(fmaxf(acc[p][k] + bE2s[k], 0.f), E3s[k], dot);
        const float z = dot + bE3v;
        prob[p] = 1.0f / (1.0f + __expf(-z));
    }

    float sacc[4] = {0.f, 0.f, 0.f, 0.f};
#pragma unroll
    for (int k = 0; k < 32; ++k) {
        const float2 sa = *(const float2*)&siT[k * 18 + i0];
        const float2 sb = *(const float2*)&sjT[k * 66 + j0];
        const float s2k = S2s[k];
        sacc[0] = fmaf(fmaxf(sa.x + sb.x, 0.f), s2k, sacc[0]);
        sacc[1] = fmaf(fmaxf(sa.x + sb.y, 0.f), s2k, sacc[1]);
        sacc[2] = fmaf(fmaxf(sa.y + sb.x, 0.f), s2k, sacc[2]);
        sacc[3] = fmaf(fmaxf(sa.y + sb.y, 0.f), s2k, sacc[3]);
    }

#pragma unroll
    for (int di = 0; di < 2; ++di) {
        const int i = qi * 16 + i0 + di;
        const int p0 = 2 * di;
        float2 av, sv;
        const float a0 = prob[p0], a1 = prob[p0 + 1];
        av.x = (i == j0     || !(a0 > 0.3f)) ? 0.f : a0;
        av.y = (i == j0 + 1 || !(a1 > 0.3f)) ? 0.f : a1;
        sv.x = (i == j0    ) ? 0.f : tanhf(sacc[p0]     + bS2v);
        sv.y = (i == j0 + 1) ? 0.f : tanhf(sacc[p0 + 1] + bS2v);
        *(float2*)(out_adj + (size_t)b * 4096 + (size_t)i * 64 + j0) = av;
        *(float2*)(out_str + (size_t)b * 4096 + (size_t)i * 64 + j0) = sv;
    }
}

extern "C" void kernel_launch(void* const* d_in, const int* in_sizes, int n_in,
                              void* d_out, int out_size, void* d_ws, size_t ws_size,
                              hipStream_t stream)
{
    const float* x     = (const float*)d_in[0];
    const float* W1    = (const float*)d_in[1];
    const float* b1    = (const float*)d_in[2];
    const float* W2    = (const float*)d_in[3];
    const float* b2    = (const float*)d_in[4];
    const float* gamma = (const float*)d_in[5];
    const float* beta  = (const float*)d_in[6];
    const float* E1    = (const float*)d_in[7];
    const float* bE1   = (const float*)d_in[8];
    const float* E2    = (const float*)d_in[9];
    const float* bE2   = (const float*)d_in[10];
    const float* E3    = (const float*)d_in[11];
    const float* bE3   = (const float*)d_in[12];
    const float* S1    = (const float*)d_in[13];
    const float* bS1   = (const float*)d_in[14];
    const float* S2    = (const float*)d_in[15];
    const float* bS2   = (const float*)d_in[16];

    float* out     = (float*)d_out;
    float* out_nf  = out;                // 256*64*64
    float* out_adj = out + 1048576;
    float* out_str = out + 2097152;

    float* ws    = (float*)d_ws;
    float* ws_ei = ws;                   // 1048576
    float* ws_ej = ws + 1048576;         // 1048576
    float* ws_si = ws + 2097152;         // 524288
    float* ws_sj = ws + 2621440;         // 524288  (total 12 MB)

    (void)hipFuncSetAttribute((const void*)kernelA,
        hipFuncAttributeMaxDynamicSharedMemorySize, LDS_FLOATS * 4);

    kernelA<<<256, 256, LDS_FLOATS * 4, stream>>>(
        x, W1, b1, W2, b2, gamma, beta, E1, S1,
        out_nf, ws_ei, ws_ej, ws_si, ws_sj);

    kernelB<<<dim3(4, 256), 256, 0, stream>>>(
        ws_ei, ws_ej, ws_si, ws_sj,
        bE1, E2, bE2, E3, bE3, bS1, S2, bS2,
        out_adj, out_str);
}

// Round 3
// 170.007 us; speedup vs baseline: 1.0530x; 1.0530x over previous
//
#include <hip/hip_runtime.h>
#include <math.h>

// Problem dims (fixed by reference)
constexpr int D   = 256;   // state dim
constexpr int D2  = 128;   // hidden 1
constexpr int D4  = 64;    // hidden 2 / node feature dim
constexpr int NN  = 64;    // MAX_NODES

// ---- Kernel A LDS layout (floats), dynamic shared ----
constexpr int XT_S   = 68;                       // Xt [256][68]  (x-tile transposed [k][n])
constexpr int H1_S   = 68;                       // H1t [128][68] (h1 transposed [c][n])
constexpr int HS_S   = 68;                       // Hs  [64][68]  (h row-major [n][c])
constexpr int NF_S   = 68;                       // NFs [64][68]  (nf transposed [c][n])
constexpr int WCAT_S = 196;                      // Wcat [64][196]
constexpr int OFF_XT   = 0;
constexpr int OFF_WC   = 256 * XT_S;             // 17408 ; W1 chunk [64][128] / W2 [128][64]
constexpr int OFF_H1T  = OFF_WC + 64 * 128;      // 25600
constexpr int LDS_FLOATS = OFF_H1T + 128 * H1_S; // 34304 floats = 137216 B
constexpr int OFF_HS   = 0;                      // aliases dead Xt region
constexpr int OFF_NFS  = 64 * HS_S;              // 4352 (still inside Xt region)
constexpr int OFF_WCAT = OFF_WC;                 // aliases dead Wc+H1t region

__global__ __launch_bounds__(256)
void kernelA(const float* __restrict__ x,
             const float* __restrict__ W1, const float* __restrict__ b1,
             const float* __restrict__ W2, const float* __restrict__ b2,
             const float* __restrict__ gamma, const float* __restrict__ beta,
             const float* __restrict__ E1, const float* __restrict__ S1,
             float* __restrict__ out_nf,
             float* __restrict__ ws_ei, float* __restrict__ ws_ej,
             float* __restrict__ ws_si, float* __restrict__ ws_sj)
{
    extern __shared__ float lds[];
    const int t = threadIdx.x;
    const int b = blockIdx.x;
    const int w = t >> 6, l = t & 63, g = l >> 3, m = l & 7;

    // ---- load x-tile transposed: Xt[k][n] = state[b][idx[n]][k] ----
    {
        const int n = t >> 2;
        // replicate jnp.linspace(0,127,64,f32).astype(int32): endpoint pinned
        const int srow = (n == 63) ? 127 : (int)((float)n * (127.0f / 63.0f));
        const float* src = x + ((size_t)b * 128 + srow) * D;
        const int c4b = (t & 3) * 16;
#pragma unroll
        for (int i = 0; i < 16; ++i) {
            const int k = 4 * (c4b + i);
            const float4 v = *(const float4*)(src + k);
            lds[OFF_XT + (k + 0) * XT_S + n] = v.x;
            lds[OFF_XT + (k + 1) * XT_S + n] = v.y;
            lds[OFF_XT + (k + 2) * XT_S + n] = v.z;
            lds[OFF_XT + (k + 3) * XT_S + n] = v.w;
        }
    }

    // ---- phase 2: h1 = relu(x @ W1 + b1)  (64 rows x 128 cols, K=256) ----
    float acc[8][4];
#pragma unroll
    for (int r = 0; r < 8; ++r) { acc[r][0]=0.f; acc[r][1]=0.f; acc[r][2]=0.f; acc[r][3]=0.f; }
    const int c0 = 32 * w + 4 * m;     // this thread's 4 output cols
    for (int ch = 0; ch < 4; ++ch) {
        __syncthreads();
        // stage W1 chunk rows [64ch, 64ch+64) -> Wc[64][128]
#pragma unroll
        for (int i = 0; i < 8; ++i) {
            const int f = t + 256 * i;               // 2048 float4
            const int kk = f >> 5, col4 = (f & 31) * 4;
            *(float4*)&lds[OFF_WC + kk * 128 + col4] =
                *(const float4*)(W1 + (size_t)(ch * 64 + kk) * D2 + col4);
        }
        __syncthreads();
        for (int kk = 0; kk < 64; ++kk) {
            const float4 xa = *(const float4*)&lds[OFF_XT + (ch * 64 + kk) * XT_S + 8 * g];
            const float4 xb = *(const float4*)&lds[OFF_XT + (ch * 64 + kk) * XT_S + 8 * g + 4];
            const float4 wv = *(const float4*)&lds[OFF_WC + kk * 128 + c0];
            const float xr[8] = {xa.x, xa.y, xa.z, xa.w, xb.x, xb.y, xb.z, xb.w};
            const float wc[4] = {wv.x, wv.y, wv.z, wv.w};
#pragma unroll
            for (int r = 0; r < 8; ++r)
#pragma unroll
                for (int c = 0; c < 4; ++c)
                    acc[r][c] = fmaf(xr[r], wc[c], acc[r][c]);
        }
    }
    // write h1 transposed to H1t[c][n] with relu + b1
    {
        const float4 b1v = *(const float4*)(b1 + c0);
        const float bb4[4] = {b1v.x, b1v.y, b1v.z, b1v.w};
#pragma unroll
        for (int c = 0; c < 4; ++c) {
            float4 lo, hi;
            lo.x = fmaxf(acc[0][c] + bb4[c], 0.f); lo.y = fmaxf(acc[1][c] + bb4[c], 0.f);
            lo.z = fmaxf(acc[2][c] + bb4[c], 0.f); lo.w = fmaxf(acc[3][c] + bb4[c], 0.f);
            hi.x = fmaxf(acc[4][c] + bb4[c], 0.f); hi.y = fmaxf(acc[5][c] + bb4[c], 0.f);
            hi.z = fmaxf(acc[6][c] + bb4[c], 0.f); hi.w = fmaxf(acc[7][c] + bb4[c], 0.f);
            *(float4*)&lds[OFF_H1T + (c0 + c) * H1_S + 8 * g]     = lo;
            *(float4*)&lds[OFF_H1T + (c0 + c) * H1_S + 8 * g + 4] = hi;
        }
    }
    __syncthreads();
    // stage W2 [128][64] into Wc region
#pragma unroll
    for (int i = 0; i < 8; ++i) {
        const int f = t + 256 * i;                   // 2048 float4
        const int kk = f >> 4, col4 = (f & 15) * 4;
        *(float4*)&lds[OFF_WC + kk * 64 + col4] =
            *(const float4*)(W2 + (size_t)kk * D4 + col4);
    }
    __syncthreads();

    // ---- phase 3: h = h1 @ W2 + b2 (64x64, K=128) ----
    float acc3[8][2];
#pragma unroll
    for (int r = 0; r < 8; ++r) { acc3[r][0] = 0.f; acc3[r][1] = 0.f; }
    const int c3 = 16 * w + 2 * m;
    for (int kk = 0; kk < 128; ++kk) {
        const float4 ha = *(const float4*)&lds[OFF_H1T + kk * H1_S + 8 * g];
        const float4 hb = *(const float4*)&lds[OFF_H1T + kk * H1_S + 8 * g + 4];
        const float2 wv = *(const float2*)&lds[OFF_WC + kk * 64 + c3];
        const float hr[8] = {ha.x, ha.y, ha.z, ha.w, hb.x, hb.y, hb.z, hb.w};
#pragma unroll
        for (int r = 0; r < 8; ++r) {
            acc3[r][0] = fmaf(hr[r], wv.x, acc3[r][0]);
            acc3[r][1] = fmaf(hr[r], wv.y, acc3[r][1]);
        }
    }
    {
        const float2 b2v = *(const float2*)(b2 + c3);
#pragma unroll
        for (int r = 0; r < 8; ++r) {
            float2 hv; hv.x = acc3[r][0] + b2v.x; hv.y = acc3[r][1] + b2v.y;
            *(float2*)&lds[OFF_HS + (8 * g + r) * HS_S + c3] = hv;   // Hs row-major
        }
    }
    __syncthreads();   // Hs complete; Wc/H1t now dead

    // ---- stage Wcat [64][196] = [E1a | E1b | S1a | S1b] (contraction k = nf col) ----
#pragma unroll
    for (int i = 0; i < 4; ++i) {  // E1 rows 0..63 -> cols [0,64)
        const int f = t + 256 * i; const int k = f >> 4, c4 = (f & 15) * 4;
        *(float4*)&lds[OFF_WCAT + k * WCAT_S + c4] = *(const float4*)(E1 + (size_t)k * D4 + c4);
    }
#pragma unroll
    for (int i = 0; i < 4; ++i) {  // E1 rows 64..127 -> cols [64,128)
        const int f = t + 256 * i; const int k = f >> 4, c4 = (f & 15) * 4;
        *(float4*)&lds[OFF_WCAT + k * WCAT_S + 64 + c4] = *(const float4*)(E1 + (size_t)(64 + k) * D4 + c4);
    }
#pragma unroll
    for (int i = 0; i < 2; ++i) {  // S1 rows 0..63 -> cols [128,160)
        const int f = t + 256 * i; const int k = f >> 3, c4 = (f & 7) * 4;
        *(float4*)&lds[OFF_WCAT + k * WCAT_S + 128 + c4] = *(const float4*)(S1 + (size_t)k * 32 + c4);
    }
#pragma unroll
    for (int i = 0; i < 2; ++i) {  // S1 rows 64..127 -> cols [160,192)
        const int f = t + 256 * i; const int k = f >> 3, c4 = (f & 7) * 4;
        *(float4*)&lds[OFF_WCAT + k * WCAT_S + 160 + c4] = *(const float4*)(S1 + (size_t)(64 + k) * 32 + c4);
    }

    // ---- phase 4: LayerNorm per row (two-pass, matches reference) ----
    {
        const int r4 = t >> 2, q = t & 3;   // 4 lanes per row, 16 cols each
        float vb[16];
        float s = 0.f;
#pragma unroll
        for (int d = 0; d < 4; ++d) {
            const float4 v = *(const float4*)&lds[OFF_HS + r4 * HS_S + 16 * q + 4 * d];
            vb[4*d+0] = v.x; vb[4*d+1] = v.y; vb[4*d+2] = v.z; vb[4*d+3] = v.w;
            s += v.x + v.y + v.z + v.w;
        }
        s += __shfl_xor(s, 1); s += __shfl_xor(s, 2);
        const float mu = s * (1.0f / 64.0f);
        float vs = 0.f;
#pragma unroll
        for (int e = 0; e < 16; ++e) { const float dd = vb[e] - mu; vs = fmaf(dd, dd, vs); }
        vs += __shfl_xor(vs, 1); vs += __shfl_xor(vs, 2);
        const float rstd = rsqrtf(vs * (1.0f / 64.0f) + 1e-5f);
#pragma unroll
        for (int d = 0; d < 4; ++d) {
            const float4 gv = *(const float4*)(gamma + 16 * q + 4 * d);
            const float4 bv = *(const float4*)(beta  + 16 * q + 4 * d);
            float4 o;
            o.x = fmaf((vb[4*d+0] - mu) * rstd, gv.x, bv.x);
            o.y = fmaf((vb[4*d+1] - mu) * rstd, gv.y, bv.y);
            o.z = fmaf((vb[4*d+2] - mu) * rstd, gv.z, bv.z);
            o.w = fmaf((vb[4*d+3] - mu) * rstd, gv.w, bv.w);
            *(float4*)(out_nf + (size_t)b * 4096 + (size_t)r4 * 64 + 16 * q + 4 * d) = o;
            // transposed copy for phase 5
            lds[OFF_NFS + (16*q + 4*d + 0) * NF_S + r4] = o.x;
            lds[OFF_NFS + (16*q + 4*d + 1) * NF_S + r4] = o.y;
            lds[OFF_NFS + (16*q + 4*d + 2) * NF_S + r4] = o.z;
            lds[OFF_NFS + (16*q + 4*d + 3) * NF_S + r4] = o.w;
        }
    }
    __syncthreads();

    // ---- phase 5: [ei|ej|si|sj] = nf @ Wcat  (64 x 192, K=64) ----
    float a5[8][6];
#pragma unroll
    for (int r = 0; r < 8; ++r)
#pragma unroll
        for (int c = 0; c < 6; ++c) a5[r][c] = 0.f;
    const int c5 = 48 * w + 6 * m;
    for (int kk = 0; kk < 64; ++kk) {
        const float4 na = *(const float4*)&lds[OFF_NFS + kk * NF_S + 8 * g];
        const float4 nb = *(const float4*)&lds[OFF_NFS + kk * NF_S + 8 * g + 4];
        const float2 w01 = *(const float2*)&lds[OFF_WCAT + kk * WCAT_S + c5];
        const float2 w23 = *(const float2*)&lds[OFF_WCAT + kk * WCAT_S + c5 + 2];
        const float2 w45 = *(const float2*)&lds[OFF_WCAT + kk * WCAT_S + c5 + 4];
        const float nr[8] = {na.x, na.y, na.z, na.w, nb.x, nb.y, nb.z, nb.w};
        const float wr[6] = {w01.x, w01.y, w23.x, w23.y, w45.x, w45.y};
#pragma unroll
        for (int r = 0; r < 8; ++r)
#pragma unroll
            for (int c = 0; c < 6; ++c)
                a5[r][c] = fmaf(nr[r], wr[c], a5[r][c]);
    }
    // scatter to workspace
#pragma unroll
    for (int cc = 0; cc < 6; ++cc) {
        const int c = c5 + cc;
        float* dst;
        int rs;
        if (c < 64)       { dst = ws_ei + (size_t)b * 4096 + c;        rs = 64; }
        else if (c < 128) { dst = ws_ej + (size_t)b * 4096 + (c - 64); rs = 64; }
        else if (c < 160) { dst = ws_si + (size_t)b * 2048 + (c - 128); rs = 32; }
        else              { dst = ws_sj + (size_t)b * 2048 + (c - 160); rs = 32; }
#pragma unroll
        for (int r = 0; r < 8; ++r)
            dst[(size_t)(8 * g + r) * rs] = a5[r][cc];
    }
}

// ---- Kernel B: per (b, i-octant) edge/strength MLP over 8x64 pairs ----
// Round 3 change: acc shrunk 4x32 -> 2x32 (was spilling at VGPR=128: FETCH_SIZE
// 229MB vs 12MB real). 8 i-rows x 64 j per block, 2048 blocks, 4 waves/SIMD.
__global__ __launch_bounds__(256, 4)
void kernelB(const float* __restrict__ ws_ei, const float* __restrict__ ws_ej,
             const float* __restrict__ ws_si, const float* __restrict__ ws_sj,
             const float* __restrict__ bE1, const float* __restrict__ E2,
             const float* __restrict__ bE2, const float* __restrict__ E3,
             const float* __restrict__ bE3, const float* __restrict__ bS1,
             const float* __restrict__ S2, const float* __restrict__ bS2,
             float* __restrict__ out_adj, float* __restrict__ out_str)
{
    __shared__ float eisT[64 * 10];   // [h][i_local 8], bE1 folded, pad->10
    __shared__ float ejT [64 * 66];   // [h][j]
    __shared__ float siT [32 * 10];   // [k][i_local 8], bS1 folded
    __shared__ float sjT [32 * 66];   // [k][j]
    __shared__ float e2s [64 * 32];   // E2 row-major
    __shared__ float E3s[32], S2s[32], bE2s[32];

    const int t  = threadIdx.x;
    const int qi = blockIdx.x;        // i-octant 0..7 (8 rows each)
    const int b  = blockIdx.y;        // batch 0..255

#pragma unroll
    for (int i = 0; i < 2; ++i) {     // eisT: 512
        const int f = t + 256 * i; const int r = f >> 6, h = f & 63;
        eisT[h * 10 + r] = ws_ei[(size_t)b * 4096 + (size_t)(qi * 8 + r) * 64 + h] + bE1[h];
    }
#pragma unroll
    for (int i = 0; i < 16; ++i) {    // ejT: 4096
        const int f = t + 256 * i; const int r = f >> 6, h = f & 63;
        ejT[h * 66 + r] = ws_ej[(size_t)b * 4096 + (size_t)r * 64 + h];
    }
    {                                  // siT: 256
        const int r = t >> 5, k = t & 31;
        siT[k * 10 + r] = ws_si[(size_t)b * 2048 + (size_t)(qi * 8 + r) * 32 + k] + bS1[k];
    }
#pragma unroll
    for (int i = 0; i < 8; ++i) {     // sjT: 2048
        const int f = t + 256 * i; const int r = f >> 5, k = f & 31;
        sjT[k * 66 + r] = ws_sj[(size_t)b * 2048 + (size_t)r * 32 + k];
    }
#pragma unroll
    for (int i = 0; i < 2; ++i) {     // e2s: 512 float4
        const int f4 = t + 256 * i;
        ((float4*)e2s)[f4] = ((const float4*)E2)[f4];
    }
    if (t < 32) { E3s[t] = E3[t]; S2s[t] = S2[t]; bE2s[t] = bE2[t]; }
    __syncthreads();

    const int ig = t >> 5, jg = t & 31;
    const int j0 = 2 * jg;            // this thread: pair rows (i, j0), (i, j0+1)

    float acc[2][32];
#pragma unroll
    for (int p = 0; p < 2; ++p)
#pragma unroll
        for (int k = 0; k < 32; ++k) acc[p][k] = 0.f;

    for (int h = 0; h < 64; ++h) {
        const float  ea = eisT[h * 10 + ig];
        const float2 eb = *(const float2*)&ejT[h * 66 + j0];
        const float he0 = fmaxf(ea + eb.x, 0.f);
        const float he1 = fmaxf(ea + eb.y, 0.f);
#pragma unroll
        for (int k8 = 0; k8 < 8; ++k8) {
            const float4 e2v = *(const float4*)&e2s[h * 32 + 4 * k8];
            const float ev[4] = {e2v.x, e2v.y, e2v.z, e2v.w};
#pragma unroll
            for (int d = 0; d < 4; ++d) {
                acc[0][4*k8+d] = fmaf(he0, ev[d], acc[0][4*k8+d]);
                acc[1][4*k8+d] = fmaf(he1, ev[d], acc[1][4*k8+d]);
            }
        }
    }

    const float bE3v = bE3[0], bS2v = bS2[0];
    float prob[2];
#pragma unroll
    for (int p = 0; p < 2; ++p) {
        float dot = 0.f;
#pragma unroll
        for (int k = 0; k < 32; ++k)
            dot = fmaf(fmaxf(acc[p][k] + bE2s[k], 0.f), E3s[k], dot);
        const float z = dot + bE3v;
        prob[p] = 1.0f / (1.0f + __expf(-z));
    }

    float sacc[2] = {0.f, 0.f};
#pragma unroll
    for (int k = 0; k < 32; ++k) {
        const float  sa = siT[k * 10 + ig];
        const float2 sb = *(const float2*)&sjT[k * 66 + j0];
        const float s2k = S2s[k];
        sacc[0] = fmaf(fmaxf(sa + sb.x, 0.f), s2k, sacc[0]);
        sacc[1] = fmaf(fmaxf(sa + sb.y, 0.f), s2k, sacc[1]);
    }

    {
        const int i = qi * 8 + ig;
        float2 av, sv;
        av.x = (i == j0     || !(prob[0] > 0.3f)) ? 0.f : prob[0];
        av.y = (i == j0 + 1 || !(prob[1] > 0.3f)) ? 0.f : prob[1];
        sv.x = (i == j0    ) ? 0.f : tanhf(sacc[0] + bS2v);
        sv.y = (i == j0 + 1) ? 0.f : tanhf(sacc[1] + bS2v);
        *(float2*)(out_adj + (size_t)b * 4096 + (size_t)i * 64 + j0) = av;
        *(float2*)(out_str + (size_t)b * 4096 + (size_t)i * 64 + j0) = sv;
    }
}

extern "C" void kernel_launch(void* const* d_in, const int* in_sizes, int n_in,
                              void* d_out, int out_size, void* d_ws, size_t ws_size,
                              hipStream_t stream)
{
    const float* x     = (const float*)d_in[0];
    const float* W1    = (const float*)d_in[1];
    const float* b1    = (const float*)d_in[2];
    const float* W2    = (const float*)d_in[3];
    const float* b2    = (const float*)d_in[4];
    const float* gamma = (const float*)d_in[5];
    const float* beta  = (const float*)d_in[6];
    const float* E1    = (const float*)d_in[7];
    const float* bE1   = (const float*)d_in[8];
    const float* E2    = (const float*)d_in[9];
    const float* bE2   = (const float*)d_in[10];
    const float* E3    = (const float*)d_in[11];
    const float* bE3   = (const float*)d_in[12];
    const float* S1    = (const float*)d_in[13];
    const float* bS1   = (const float*)d_in[14];
    const float* S2    = (const float*)d_in[15];
    const float* bS2   = (const float*)d_in[16];

    float* out     = (float*)d_out;
    float* out_nf  = out;                // 256*64*64
    float* out_adj = out + 1048576;
    float* out_str = out + 2097152;

    float* ws    = (float*)d_ws;
    float* ws_ei = ws;                   // 1048576
    float* ws_ej = ws + 1048576;         // 1048576
    float* ws_si = ws + 2097152;         // 524288
    float* ws_sj = ws + 2621440;         // 524288  (total 12 MB)

    (void)hipFuncSetAttribute((const void*)kernelA,
        hipFuncAttributeMaxDynamicSharedMemorySize, LDS_FLOATS * 4);

    kernelA<<<256, 256, LDS_FLOATS * 4, stream>>>(
        x, W1, b1, W2, b2, gamma, beta, E1, S1,
        out_nf, ws_ei, ws_ej, ws_si, ws_sj);

    kernelB<<<dim3(8, 256), 256, 0, stream>>>(
        ws_ei, ws_ej, ws_si, ws_sj,
        bE1, E2, bE2, E3, bE3, bS1, S2, bS2,
        out_adj, out_str);
}

// Round 4
// 136.356 us; speedup vs baseline: 1.3128x; 1.2468x over previous
//
#include <hip/hip_runtime.h>
#include <math.h>

// Problem dims (fixed by reference)
constexpr int D   = 256;   // state dim
constexpr int D2  = 128;   // hidden 1
constexpr int D4  = 64;    // hidden 2 / node feature dim
constexpr int NN  = 64;    // MAX_NODES

// ---- Kernel A LDS layout (floats), dynamic shared ----
constexpr int XT_S   = 68;                       // Xt [256][68]  (x-tile transposed [k][n])
constexpr int H1_S   = 68;                       // H1t [128][68] (h1 transposed [c][n])
constexpr int HS_S   = 68;                       // Hs  [64][68]  (h row-major [n][c])
constexpr int NF_S   = 68;                       // NFs [64][68]  (nf transposed [c][n])
constexpr int WCAT_S = 196;                      // Wcat [64][196]
constexpr int OFF_XT   = 0;
constexpr int OFF_WC   = 256 * XT_S;             // 17408 ; W1 chunk [64][128] / W2 [128][64]
constexpr int OFF_H1T  = OFF_WC + 64 * 128;      // 25600
constexpr int LDS_FLOATS = OFF_H1T + 128 * H1_S; // 34304 floats = 137216 B
constexpr int OFF_HS   = 0;                      // aliases dead Xt region
constexpr int OFF_NFS  = 64 * HS_S;              // 4352 (still inside Xt region)
constexpr int OFF_WCAT = OFF_WC;                 // aliases dead Wc+H1t region

__global__ __launch_bounds__(256)
void kernelA(const float* __restrict__ x,
             const float* __restrict__ W1, const float* __restrict__ b1,
             const float* __restrict__ W2, const float* __restrict__ b2,
             const float* __restrict__ gamma, const float* __restrict__ beta,
             const float* __restrict__ E1, const float* __restrict__ S1,
             float* __restrict__ out_nf,
             float* __restrict__ ws_ei, float* __restrict__ ws_ej,
             float* __restrict__ ws_si, float* __restrict__ ws_sj)
{
    extern __shared__ float lds[];
    const int t = threadIdx.x;
    const int b = blockIdx.x;
    const int w = t >> 6, l = t & 63, g = l >> 3, m = l & 7;

    // ---- load x-tile transposed: Xt[k][n] = state[b][idx[n]][k] ----
    {
        const int n = t >> 2;
        // replicate jnp.linspace(0,127,64,f32).astype(int32): endpoint pinned
        const int srow = (n == 63) ? 127 : (int)((float)n * (127.0f / 63.0f));
        const float* src = x + ((size_t)b * 128 + srow) * D;
        const int c4b = (t & 3) * 16;
#pragma unroll
        for (int i = 0; i < 16; ++i) {
            const int k = 4 * (c4b + i);
            const float4 v = *(const float4*)(src + k);
            lds[OFF_XT + (k + 0) * XT_S + n] = v.x;
            lds[OFF_XT + (k + 1) * XT_S + n] = v.y;
            lds[OFF_XT + (k + 2) * XT_S + n] = v.z;
            lds[OFF_XT + (k + 3) * XT_S + n] = v.w;
        }
    }

    // ---- phase 2: h1 = relu(x @ W1 + b1)  (64 rows x 128 cols, K=256) ----
    float acc[8][4];
#pragma unroll
    for (int r = 0; r < 8; ++r) { acc[r][0]=0.f; acc[r][1]=0.f; acc[r][2]=0.f; acc[r][3]=0.f; }
    const int c0 = 32 * w + 4 * m;     // this thread's 4 output cols
    for (int ch = 0; ch < 4; ++ch) {
        __syncthreads();
        // stage W1 chunk rows [64ch, 64ch+64) -> Wc[64][128]
#pragma unroll
        for (int i = 0; i < 8; ++i) {
            const int f = t + 256 * i;               // 2048 float4
            const int kk = f >> 5, col4 = (f & 31) * 4;
            *(float4*)&lds[OFF_WC + kk * 128 + col4] =
                *(const float4*)(W1 + (size_t)(ch * 64 + kk) * D2 + col4);
        }
        __syncthreads();
        for (int kk = 0; kk < 64; ++kk) {
            const float4 xa = *(const float4*)&lds[OFF_XT + (ch * 64 + kk) * XT_S + 8 * g];
            const float4 xb = *(const float4*)&lds[OFF_XT + (ch * 64 + kk) * XT_S + 8 * g + 4];
            const float4 wv = *(const float4*)&lds[OFF_WC + kk * 128 + c0];
            const float xr[8] = {xa.x, xa.y, xa.z, xa.w, xb.x, xb.y, xb.z, xb.w};
            const float wc[4] = {wv.x, wv.y, wv.z, wv.w};
#pragma unroll
            for (int r = 0; r < 8; ++r)
#pragma unroll
                for (int c = 0; c < 4; ++c)
                    acc[r][c] = fmaf(xr[r], wc[c], acc[r][c]);
        }
    }
    // write h1 transposed to H1t[c][n] with relu + b1
    {
        const float4 b1v = *(const float4*)(b1 + c0);
        const float bb4[4] = {b1v.x, b1v.y, b1v.z, b1v.w};
#pragma unroll
        for (int c = 0; c < 4; ++c) {
            float4 lo, hi;
            lo.x = fmaxf(acc[0][c] + bb4[c], 0.f); lo.y = fmaxf(acc[1][c] + bb4[c], 0.f);
            lo.z = fmaxf(acc[2][c] + bb4[c], 0.f); lo.w = fmaxf(acc[3][c] + bb4[c], 0.f);
            hi.x = fmaxf(acc[4][c] + bb4[c], 0.f); hi.y = fmaxf(acc[5][c] + bb4[c], 0.f);
            hi.z = fmaxf(acc[6][c] + bb4[c], 0.f); hi.w = fmaxf(acc[7][c] + bb4[c], 0.f);
            *(float4*)&lds[OFF_H1T + (c0 + c) * H1_S + 8 * g]     = lo;
            *(float4*)&lds[OFF_H1T + (c0 + c) * H1_S + 8 * g + 4] = hi;
        }
    }
    __syncthreads();
    // stage W2 [128][64] into Wc region
#pragma unroll
    for (int i = 0; i < 8; ++i) {
        const int f = t + 256 * i;                   // 2048 float4
        const int kk = f >> 4, col4 = (f & 15) * 4;
        *(float4*)&lds[OFF_WC + kk * 64 + col4] =
            *(const float4*)(W2 + (size_t)kk * D4 + col4);
    }
    __syncthreads();

    // ---- phase 3: h = h1 @ W2 + b2 (64x64, K=128) ----
    float acc3[8][2];
#pragma unroll
    for (int r = 0; r < 8; ++r) { acc3[r][0] = 0.f; acc3[r][1] = 0.f; }
    const int c3 = 16 * w + 2 * m;
    for (int kk = 0; kk < 128; ++kk) {
        const float4 ha = *(const float4*)&lds[OFF_H1T + kk * H1_S + 8 * g];
        const float4 hb = *(const float4*)&lds[OFF_H1T + kk * H1_S + 8 * g + 4];
        const float2 wv = *(const float2*)&lds[OFF_WC + kk * 64 + c3];
        const float hr[8] = {ha.x, ha.y, ha.z, ha.w, hb.x, hb.y, hb.z, hb.w};
#pragma unroll
        for (int r = 0; r < 8; ++r) {
            acc3[r][0] = fmaf(hr[r], wv.x, acc3[r][0]);
            acc3[r][1] = fmaf(hr[r], wv.y, acc3[r][1]);
        }
    }
    {
        const float2 b2v = *(const float2*)(b2 + c3);
#pragma unroll
        for (int r = 0; r < 8; ++r) {
            float2 hv; hv.x = acc3[r][0] + b2v.x; hv.y = acc3[r][1] + b2v.y;
            *(float2*)&lds[OFF_HS + (8 * g + r) * HS_S + c3] = hv;   // Hs row-major
        }
    }
    __syncthreads();   // Hs complete; Wc/H1t now dead

    // ---- stage Wcat [64][196] = [E1a | E1b | S1a | S1b] (contraction k = nf col) ----
#pragma unroll
    for (int i = 0; i < 4; ++i) {  // E1 rows 0..63 -> cols [0,64)
        const int f = t + 256 * i; const int k = f >> 4, c4 = (f & 15) * 4;
        *(float4*)&lds[OFF_WCAT + k * WCAT_S + c4] = *(const float4*)(E1 + (size_t)k * D4 + c4);
    }
#pragma unroll
    for (int i = 0; i < 4; ++i) {  // E1 rows 64..127 -> cols [64,128)
        const int f = t + 256 * i; const int k = f >> 4, c4 = (f & 15) * 4;
        *(float4*)&lds[OFF_WCAT + k * WCAT_S + 64 + c4] = *(const float4*)(E1 + (size_t)(64 + k) * D4 + c4);
    }
#pragma unroll
    for (int i = 0; i < 2; ++i) {  // S1 rows 0..63 -> cols [128,160)
        const int f = t + 256 * i; const int k = f >> 3, c4 = (f & 7) * 4;
        *(float4*)&lds[OFF_WCAT + k * WCAT_S + 128 + c4] = *(const float4*)(S1 + (size_t)k * 32 + c4);
    }
#pragma unroll
    for (int i = 0; i < 2; ++i) {  // S1 rows 64..127 -> cols [160,192)
        const int f = t + 256 * i; const int k = f >> 3, c4 = (f & 7) * 4;
        *(float4*)&lds[OFF_WCAT + k * WCAT_S + 160 + c4] = *(const float4*)(S1 + (size_t)(64 + k) * 32 + c4);
    }

    // ---- phase 4: LayerNorm per row (two-pass, matches reference) ----
    {
        const int r4 = t >> 2, q = t & 3;   // 4 lanes per row, 16 cols each
        float vb[16];
        float s = 0.f;
#pragma unroll
        for (int d = 0; d < 4; ++d) {
            const float4 v = *(const float4*)&lds[OFF_HS + r4 * HS_S + 16 * q + 4 * d];
            vb[4*d+0] = v.x; vb[4*d+1] = v.y; vb[4*d+2] = v.z; vb[4*d+3] = v.w;
            s += v.x + v.y + v.z + v.w;
        }
        s += __shfl_xor(s, 1); s += __shfl_xor(s, 2);
        const float mu = s * (1.0f / 64.0f);
        float vs = 0.f;
#pragma unroll
        for (int e = 0; e < 16; ++e) { const float dd = vb[e] - mu; vs = fmaf(dd, dd, vs); }
        vs += __shfl_xor(vs, 1); vs += __shfl_xor(vs, 2);
        const float rstd = rsqrtf(vs * (1.0f / 64.0f) + 1e-5f);
#pragma unroll
        for (int d = 0; d < 4; ++d) {
            const float4 gv = *(const float4*)(gamma + 16 * q + 4 * d);
            const float4 bv = *(const float4*)(beta  + 16 * q + 4 * d);
            float4 o;
            o.x = fmaf((vb[4*d+0] - mu) * rstd, gv.x, bv.x);
            o.y = fmaf((vb[4*d+1] - mu) * rstd, gv.y, bv.y);
            o.z = fmaf((vb[4*d+2] - mu) * rstd, gv.z, bv.z);
            o.w = fmaf((vb[4*d+3] - mu) * rstd, gv.w, bv.w);
            *(float4*)(out_nf + (size_t)b * 4096 + (size_t)r4 * 64 + 16 * q + 4 * d) = o;
            // transposed copy for phase 5
            lds[OFF_NFS + (16*q + 4*d + 0) * NF_S + r4] = o.x;
            lds[OFF_NFS + (16*q + 4*d + 1) * NF_S + r4] = o.y;
            lds[OFF_NFS + (16*q + 4*d + 2) * NF_S + r4] = o.z;
            lds[OFF_NFS + (16*q + 4*d + 3) * NF_S + r4] = o.w;
        }
    }
    __syncthreads();

    // ---- phase 5: [ei|ej|si|sj] = nf @ Wcat  (64 x 192, K=64) ----
    float a5[8][6];
#pragma unroll
    for (int r = 0; r < 8; ++r)
#pragma unroll
        for (int c = 0; c < 6; ++c) a5[r][c] = 0.f;
    const int c5 = 48 * w + 6 * m;
    for (int kk = 0; kk < 64; ++kk) {
        const float4 na = *(const float4*)&lds[OFF_NFS + kk * NF_S + 8 * g];
        const float4 nb = *(const float4*)&lds[OFF_NFS + kk * NF_S + 8 * g + 4];
        const float2 w01 = *(const float2*)&lds[OFF_WCAT + kk * WCAT_S + c5];
        const float2 w23 = *(const float2*)&lds[OFF_WCAT + kk * WCAT_S + c5 + 2];
        const float2 w45 = *(const float2*)&lds[OFF_WCAT + kk * WCAT_S + c5 + 4];
        const float nr[8] = {na.x, na.y, na.z, na.w, nb.x, nb.y, nb.z, nb.w};
        const float wr[6] = {w01.x, w01.y, w23.x, w23.y, w45.x, w45.y};
#pragma unroll
        for (int r = 0; r < 8; ++r)
#pragma unroll
            for (int c = 0; c < 6; ++c)
                a5[r][c] = fmaf(nr[r], wr[c], a5[r][c]);
    }
    // scatter to workspace
#pragma unroll
    for (int cc = 0; cc < 6; ++cc) {
        const int c = c5 + cc;
        float* dst;
        int rs;
        if (c < 64)       { dst = ws_ei + (size_t)b * 4096 + c;        rs = 64; }
        else if (c < 128) { dst = ws_ej + (size_t)b * 4096 + (c - 64); rs = 64; }
        else if (c < 160) { dst = ws_si + (size_t)b * 2048 + (c - 128); rs = 32; }
        else              { dst = ws_sj + (size_t)b * 2048 + (c - 160); rs = 32; }
#pragma unroll
        for (int r = 0; r < 8; ++r)
            dst[(size_t)(8 * g + r) * rs] = a5[r][cc];
    }
}

// ============================================================================
// Kernel B (round 4): MFMA edge/strength pair stage.
// Swapped operands: A-frags = E2^T / S2^T (preloaded in VGPRs -> E2 never
// re-read from LDS; kills the 1-LDS-unit-per-4-SIMD bottleneck that capped
// rounds 2/3 at ~130us). B-frags = he/hs built in f32 from LDS then cvt bf16.
// Precision: sigma(z) ~ 0.1, logit(0.3) = -0.847 is ~9 sigma away -> threshold
// never fires off-diagonal; bf16 error ~3e-3 cannot flip it.
// ============================================================================
typedef __attribute__((ext_vector_type(8))) short short8;
typedef __attribute__((ext_vector_type(4))) float f32x4;

__device__ __forceinline__ short f2bf(float f) {
    unsigned u = __builtin_bit_cast(unsigned, f);
    u += 0x7fffu + ((u >> 16) & 1u);         // RNE (no NaN in this data)
    return (short)(u >> 16);
}

// LDS strides chosen so per-lane ds_read_b128 is 16B-aligned and bank-uniform:
// ejR stride 76: bank-group (12j+8g)%32 uniform 8 lanes/group -> conflict-free.
constexpr int EJ_S = 76;
constexpr int EI_S = 68;
constexpr int SJ_S = 36;
constexpr int SI_S = 36;

__global__ __launch_bounds__(256, 4)
void kernelB(const float* __restrict__ ws_ei, const float* __restrict__ ws_ej,
             const float* __restrict__ ws_si, const float* __restrict__ ws_sj,
             const float* __restrict__ bE1, const float* __restrict__ E2,
             const float* __restrict__ bE2, const float* __restrict__ E3,
             const float* __restrict__ bE3, const float* __restrict__ bS1,
             const float* __restrict__ S2, const float* __restrict__ bS2,
             float* __restrict__ out_adj, float* __restrict__ out_str)
{
    __shared__ float ejR[64 * EJ_S];   // ej row-major [j][h], bank-spread stride
    __shared__ float eis[16 * EI_S];   // ei rows of this i-strip, bE1 folded
    __shared__ float sjR[64 * SJ_S];   // sj row-major [j][k]
    __shared__ float siR[16 * SI_S];   // si rows, bS1 folded
    __shared__ float bE2s[32], E3s[32];
    // total 35,584 B -> 4 blocks/CU (pins VGPR budget at 128, no 64-chasing)

    const int t  = threadIdx.x;
    const int qi = blockIdx.x;         // i-strip 0..3 (16 i-rows)
    const int b  = blockIdx.y;         // batch
    const int w  = t >> 6, l = t & 63;
    const int g  = l >> 4, r = l & 15;

    // ---- stage ----
#pragma unroll
    for (int it = 0; it < 16; ++it) {  // ejR: 4096
        const int f = t + 256 * it; const int j = f >> 6, h = f & 63;
        ejR[j * EJ_S + h] = ws_ej[(size_t)b * 4096 + (size_t)j * 64 + h];
    }
#pragma unroll
    for (int it = 0; it < 4; ++it) {   // eis: 1024 (+bE1)
        const int f = t + 256 * it; const int rr = f >> 6, h = f & 63;
        eis[rr * EI_S + h] = ws_ei[(size_t)b * 4096 + (size_t)(qi * 16 + rr) * 64 + h] + bE1[h];
    }
#pragma unroll
    for (int it = 0; it < 8; ++it) {   // sjR: 2048
        const int f = t + 256 * it; const int j = f >> 5, k = f & 31;
        sjR[j * SJ_S + k] = ws_sj[(size_t)b * 2048 + (size_t)j * 32 + k];
    }
#pragma unroll
    for (int it = 0; it < 2; ++it) {   // siR: 512 (+bS1)
        const int f = t + 256 * it; const int rr = f >> 5, k = f & 31;
        siR[rr * SI_S + k] = ws_si[(size_t)b * 2048 + (size_t)(qi * 16 + rr) * 32 + k] + bS1[k];
    }
    if (t < 32)       bE2s[t] = bE2[t];
    else if (t < 64)  E3s[t - 32] = E3[t - 32];

    // ---- A-frag preload (registers; E2^T and S2^T) ----
    // A[row=kout][k=h]: lane l supplies row r(+16*rt), k = 8g+e (+32s).
    short8 aE00, aE10, aE01, aE11, aS;
#pragma unroll
    for (int e = 0; e < 8; ++e) {
        aE00[e] = f2bf(E2[(size_t)(8 * g + e) * 32 + r]);            // s=0, rt=0
        aE10[e] = f2bf(E2[(size_t)(8 * g + e + 32) * 32 + r]);       // s=1, rt=0
        aE01[e] = f2bf(E2[(size_t)(8 * g + e) * 32 + r + 16]);       // s=0, rt=1
        aE11[e] = f2bf(E2[(size_t)(8 * g + e + 32) * 32 + r + 16]);  // s=1, rt=1
        aS[e]   = (r == 0) ? f2bf(S2[8 * g + e]) : (short)0;
    }
    const float bE3v = bE3[0], bS2v = bS2[0];
    __syncthreads();

    // ---- main: per wave, i-rows {4w..4w+3} x j-tiles {0,16,32,48} ----
    for (int jt = 0; jt < 4; ++jt) {
        const int j = (jt << 4) + r;                // this lane's B-column
        const float4 ej00 = *(const float4*)&ejR[j * EJ_S + 8 * g];
        const float4 ej01 = *(const float4*)&ejR[j * EJ_S + 8 * g + 4];
        const float4 ej10 = *(const float4*)&ejR[j * EJ_S + 32 + 8 * g];
        const float4 ej11 = *(const float4*)&ejR[j * EJ_S + 32 + 8 * g + 4];
        const float4 sj0  = *(const float4*)&sjR[j * SJ_S + 8 * g];
        const float4 sj1  = *(const float4*)&sjR[j * SJ_S + 8 * g + 4];

#pragma unroll
        for (int ii = 0; ii < 4; ++ii) {
            const int il = 4 * w + ii;              // i within strip
            const int ig = qi * 16 + il;            // global i
            const float4 ei00 = *(const float4*)&eis[il * EI_S + 8 * g];
            const float4 ei01 = *(const float4*)&eis[il * EI_S + 8 * g + 4];
            const float4 ei10 = *(const float4*)&eis[il * EI_S + 32 + 8 * g];
            const float4 ei11 = *(const float4*)&eis[il * EI_S + 32 + 8 * g + 4];

            short8 b0, b1;                          // he bf16, k-steps 0/1
            b0[0] = f2bf(fmaxf(ei00.x + ej00.x, 0.f));
            b0[1] = f2bf(fmaxf(ei00.y + ej00.y, 0.f));
            b0[2] = f2bf(fmaxf(ei00.z + ej00.z, 0.f));
            b0[3] = f2bf(fmaxf(ei00.w + ej00.w, 0.f));
            b0[4] = f2bf(fmaxf(ei01.x + ej01.x, 0.f));
            b0[5] = f2bf(fmaxf(ei01.y + ej01.y, 0.f));
            b0[6] = f2bf(fmaxf(ei01.z + ej01.z, 0.f));
            b0[7] = f2bf(fmaxf(ei01.w + ej01.w, 0.f));
            b1[0] = f2bf(fmaxf(ei10.x + ej10.x, 0.f));
            b1[1] = f2bf(fmaxf(ei10.y + ej10.y, 0.f));
            b1[2] = f2bf(fmaxf(ei10.z + ej10.z, 0.f));
            b1[3] = f2bf(fmaxf(ei10.w + ej10.w, 0.f));
            b1[4] = f2bf(fmaxf(ei11.x + ej11.x, 0.f));
            b1[5] = f2bf(fmaxf(ei11.y + ej11.y, 0.f));
            b1[6] = f2bf(fmaxf(ei11.z + ej11.z, 0.f));
            b1[7] = f2bf(fmaxf(ei11.w + ej11.w, 0.f));

            f32x4 acc0 = {0.f, 0.f, 0.f, 0.f};
            f32x4 acc1 = {0.f, 0.f, 0.f, 0.f};
            acc0 = __builtin_amdgcn_mfma_f32_16x16x32_bf16(aE00, b0, acc0, 0, 0, 0);
            acc0 = __builtin_amdgcn_mfma_f32_16x16x32_bf16(aE10, b1, acc0, 0, 0, 0);
            acc1 = __builtin_amdgcn_mfma_f32_16x16x32_bf16(aE01, b0, acc1, 0, 0, 0);
            acc1 = __builtin_amdgcn_mfma_f32_16x16x32_bf16(aE11, b1, acc1, 0, 0, 0);

            const float4 si0 = *(const float4*)&siR[il * SI_S + 8 * g];
            const float4 si1 = *(const float4*)&siR[il * SI_S + 8 * g + 4];
            short8 bs;
            bs[0] = f2bf(fmaxf(si0.x + sj0.x, 0.f));
            bs[1] = f2bf(fmaxf(si0.y + sj0.y, 0.f));
            bs[2] = f2bf(fmaxf(si0.z + sj0.z, 0.f));
            bs[3] = f2bf(fmaxf(si0.w + sj0.w, 0.f));
            bs[4] = f2bf(fmaxf(si1.x + sj1.x, 0.f));
            bs[5] = f2bf(fmaxf(si1.y + sj1.y, 0.f));
            bs[6] = f2bf(fmaxf(si1.z + sj1.z, 0.f));
            bs[7] = f2bf(fmaxf(si1.w + sj1.w, 0.f));
            f32x4 accS = {0.f, 0.f, 0.f, 0.f};
            accS = __builtin_amdgcn_mfma_f32_16x16x32_bf16(aS, bs, accS, 0, 0, 0);

            // ---- E epilogue: lane holds D[kout=4g+q (+16)][col j] ----
            float pe = 0.f;
#pragma unroll
            for (int q = 0; q < 4; ++q) {
                const int k0 = 4 * g + q;
                pe += fmaxf(acc0[q] + bE2s[k0], 0.f) * E3s[k0];
                pe += fmaxf(acc1[q] + bE2s[k0 + 16], 0.f) * E3s[k0 + 16];
            }
            pe += __shfl_xor(pe, 16);
            pe += __shfl_xor(pe, 32);

            if (l < 16) {                           // g==0 lanes: rows 0..3 incl. S dot
                const float z = pe + bE3v;
                const float p = 1.0f / (1.0f + __expf(-z));
                const float av = (j == ig || !(p > 0.3f)) ? 0.f : p;
                out_adj[(size_t)b * 4096 + (size_t)ig * 64 + j] = av;
                // S: D[0][j] lives in accS[0] on g==0 lanes
                const float xs = accS[0] + bS2v;
                const float e2x = __expf(2.0f * xs);
                const float sv = (j == ig) ? 0.f : (e2x - 1.0f) / (e2x + 1.0f);
                out_str[(size_t)b * 4096 + (size_t)ig * 64 + j] = sv;
            }
        }
    }
}

extern "C" void kernel_launch(void* const* d_in, const int* in_sizes, int n_in,
                              void* d_out, int out_size, void* d_ws, size_t ws_size,
                              hipStream_t stream)
{
    const float* x     = (const float*)d_in[0];
    const float* W1    = (const float*)d_in[1];
    const float* b1    = (const float*)d_in[2];
    const float* W2    = (const float*)d_in[3];
    const float* b2    = (const float*)d_in[4];
    const float* gamma = (const float*)d_in[5];
    const float* beta  = (const float*)d_in[6];
    const float* E1    = (const float*)d_in[7];
    const float* bE1   = (const float*)d_in[8];
    const float* E2    = (const float*)d_in[9];
    const float* bE2   = (const float*)d_in[10];
    const float* E3    = (const float*)d_in[11];
    const float* bE3   = (const float*)d_in[12];
    const float* S1    = (const float*)d_in[13];
    const float* bS1   = (const float*)d_in[14];
    const float* S2    = (const float*)d_in[15];
    const float* bS2   = (const float*)d_in[16];

    float* out     = (float*)d_out;
    float* out_nf  = out;                // 256*64*64
    float* out_adj = out + 1048576;
    float* out_str = out + 2097152;

    float* ws    = (float*)d_ws;
    float* ws_ei = ws;                   // 1048576
    float* ws_ej = ws + 1048576;         // 1048576
    float* ws_si = ws + 2097152;         // 524288
    float* ws_sj = ws + 2621440;         // 524288  (total 12 MB)

    (void)hipFuncSetAttribute((const void*)kernelA,
        hipFuncAttributeMaxDynamicSharedMemorySize, LDS_FLOATS * 4);

    kernelA<<<256, 256, LDS_FLOATS * 4, stream>>>(
        x, W1, b1, W2, b2, gamma, beta, E1, S1,
        out_nf, ws_ei, ws_ej, ws_si, ws_sj);

    kernelB<<<dim3(4, 256), 256, 0, stream>>>(
        ws_ei, ws_ej, ws_si, ws_sj,
        bE1, E2, bE2, E3, bE3, bS1, S2, bS2,
        out_adj, out_str);
}

// Round 5
// 85.152 us; speedup vs baseline: 2.1023x; 1.6013x over previous
//
#include <hip/hip_runtime.h>
#include <math.h>

// Problem dims (fixed by reference)
constexpr int D   = 256;   // state dim
constexpr int D2  = 128;   // hidden 1
constexpr int D4  = 64;    // hidden 2 / node feature dim
constexpr int NN  = 64;    // MAX_NODES

// ---- Kernel A LDS layout (floats), dynamic shared ----
constexpr int XT_S   = 68;                       // Xt [256][68]  (x-tile transposed [k][n])
constexpr int H1_S   = 68;                       // H1t [128][68] (h1 transposed [c][n])
constexpr int HS_S   = 68;                       // Hs  [64][68]  (h row-major [n][c])
constexpr int NF_S   = 68;                       // NFs [64][68]  (nf transposed [c][n])
constexpr int WCAT_S = 196;                      // Wcat [64][196]
constexpr int OFF_XT   = 0;
constexpr int OFF_WC   = 256 * XT_S;             // 17408 ; W1 chunk [64][128] / W2 [128][64]
constexpr int OFF_H1T  = OFF_WC + 64 * 128;      // 25600
constexpr int LDS_FLOATS = OFF_H1T + 128 * H1_S; // 34304 floats = 137216 B
constexpr int OFF_HS   = 0;                      // aliases dead Xt region
constexpr int OFF_NFS  = 64 * HS_S;              // 4352 (still inside Xt region)
constexpr int OFF_WCAT = OFF_WC;                 // aliases dead Wc+H1t region

__global__ __launch_bounds__(256)
void kernelA(const float* __restrict__ x,
             const float* __restrict__ W1, const float* __restrict__ b1,
             const float* __restrict__ W2, const float* __restrict__ b2,
             const float* __restrict__ gamma, const float* __restrict__ beta,
             const float* __restrict__ E1, const float* __restrict__ S1,
             float* __restrict__ out_nf,
             float* __restrict__ ws_ei, float* __restrict__ ws_ej,
             float* __restrict__ ws_si, float* __restrict__ ws_sj)
{
    extern __shared__ float lds[];
    const int t = threadIdx.x;
    const int b = blockIdx.x;
    const int w = t >> 6, l = t & 63, g = l >> 3, m = l & 7;

    // ---- load x-tile transposed: Xt[k][n] = state[b][idx[n]][k] ----
    {
        const int n = t >> 2;
        // replicate jnp.linspace(0,127,64,f32).astype(int32): endpoint pinned
        const int srow = (n == 63) ? 127 : (int)((float)n * (127.0f / 63.0f));
        const float* src = x + ((size_t)b * 128 + srow) * D;
        const int c4b = (t & 3) * 16;
#pragma unroll
        for (int i = 0; i < 16; ++i) {
            const int k = 4 * (c4b + i);
            const float4 v = *(const float4*)(src + k);
            lds[OFF_XT + (k + 0) * XT_S + n] = v.x;
            lds[OFF_XT + (k + 1) * XT_S + n] = v.y;
            lds[OFF_XT + (k + 2) * XT_S + n] = v.z;
            lds[OFF_XT + (k + 3) * XT_S + n] = v.w;
        }
    }

    // ---- phase 2: h1 = relu(x @ W1 + b1)  (64 rows x 128 cols, K=256) ----
    float acc[8][4];
#pragma unroll
    for (int r = 0; r < 8; ++r) { acc[r][0]=0.f; acc[r][1]=0.f; acc[r][2]=0.f; acc[r][3]=0.f; }
    const int c0 = 32 * w + 4 * m;     // this thread's 4 output cols
    for (int ch = 0; ch < 4; ++ch) {
        __syncthreads();
        // stage W1 chunk rows [64ch, 64ch+64) -> Wc[64][128]
#pragma unroll
        for (int i = 0; i < 8; ++i) {
            const int f = t + 256 * i;               // 2048 float4
            const int kk = f >> 5, col4 = (f & 31) * 4;
            *(float4*)&lds[OFF_WC + kk * 128 + col4] =
                *(const float4*)(W1 + (size_t)(ch * 64 + kk) * D2 + col4);
        }
        __syncthreads();
        for (int kk = 0; kk < 64; ++kk) {
            const float4 xa = *(const float4*)&lds[OFF_XT + (ch * 64 + kk) * XT_S + 8 * g];
            const float4 xb = *(const float4*)&lds[OFF_XT + (ch * 64 + kk) * XT_S + 8 * g + 4];
            const float4 wv = *(const float4*)&lds[OFF_WC + kk * 128 + c0];
            const float xr[8] = {xa.x, xa.y, xa.z, xa.w, xb.x, xb.y, xb.z, xb.w};
            const float wc[4] = {wv.x, wv.y, wv.z, wv.w};
#pragma unroll
            for (int r = 0; r < 8; ++r)
#pragma unroll
                for (int c = 0; c < 4; ++c)
                    acc[r][c] = fmaf(xr[r], wc[c], acc[r][c]);
        }
    }
    // write h1 transposed to H1t[c][n] with relu + b1
    {
        const float4 b1v = *(const float4*)(b1 + c0);
        const float bb4[4] = {b1v.x, b1v.y, b1v.z, b1v.w};
#pragma unroll
        for (int c = 0; c < 4; ++c) {
            float4 lo, hi;
            lo.x = fmaxf(acc[0][c] + bb4[c], 0.f); lo.y = fmaxf(acc[1][c] + bb4[c], 0.f);
            lo.z = fmaxf(acc[2][c] + bb4[c], 0.f); lo.w = fmaxf(acc[3][c] + bb4[c], 0.f);
            hi.x = fmaxf(acc[4][c] + bb4[c], 0.f); hi.y = fmaxf(acc[5][c] + bb4[c], 0.f);
            hi.z = fmaxf(acc[6][c] + bb4[c], 0.f); hi.w = fmaxf(acc[7][c] + bb4[c], 0.f);
            *(float4*)&lds[OFF_H1T + (c0 + c) * H1_S + 8 * g]     = lo;
            *(float4*)&lds[OFF_H1T + (c0 + c) * H1_S + 8 * g + 4] = hi;
        }
    }
    __syncthreads();
    // stage W2 [128][64] into Wc region
#pragma unroll
    for (int i = 0; i < 8; ++i) {
        const int f = t + 256 * i;                   // 2048 float4
        const int kk = f >> 4, col4 = (f & 15) * 4;
        *(float4*)&lds[OFF_WC + kk * 64 + col4] =
            *(const float4*)(W2 + (size_t)kk * D4 + col4);
    }
    __syncthreads();

    // ---- phase 3: h = h1 @ W2 + b2 (64x64, K=128) ----
    float acc3[8][2];
#pragma unroll
    for (int r = 0; r < 8; ++r) { acc3[r][0] = 0.f; acc3[r][1] = 0.f; }
    const int c3 = 16 * w + 2 * m;
    for (int kk = 0; kk < 128; ++kk) {
        const float4 ha = *(const float4*)&lds[OFF_H1T + kk * H1_S + 8 * g];
        const float4 hb = *(const float4*)&lds[OFF_H1T + kk * H1_S + 8 * g + 4];
        const float2 wv = *(const float2*)&lds[OFF_WC + kk * 64 + c3];
        const float hr[8] = {ha.x, ha.y, ha.z, ha.w, hb.x, hb.y, hb.z, hb.w};
#pragma unroll
        for (int r = 0; r < 8; ++r) {
            acc3[r][0] = fmaf(hr[r], wv.x, acc3[r][0]);
            acc3[r][1] = fmaf(hr[r], wv.y, acc3[r][1]);
        }
    }
    {
        const float2 b2v = *(const float2*)(b2 + c3);
#pragma unroll
        for (int r = 0; r < 8; ++r) {
            float2 hv; hv.x = acc3[r][0] + b2v.x; hv.y = acc3[r][1] + b2v.y;
            *(float2*)&lds[OFF_HS + (8 * g + r) * HS_S + c3] = hv;   // Hs row-major
        }
    }
    __syncthreads();   // Hs complete; Wc/H1t now dead

    // ---- stage Wcat [64][196] = [E1a | E1b | S1a | S1b] (contraction k = nf col) ----
#pragma unroll
    for (int i = 0; i < 4; ++i) {  // E1 rows 0..63 -> cols [0,64)
        const int f = t + 256 * i; const int k = f >> 4, c4 = (f & 15) * 4;
        *(float4*)&lds[OFF_WCAT + k * WCAT_S + c4] = *(const float4*)(E1 + (size_t)k * D4 + c4);
    }
#pragma unroll
    for (int i = 0; i < 4; ++i) {  // E1 rows 64..127 -> cols [64,128)
        const int f = t + 256 * i; const int k = f >> 4, c4 = (f & 15) * 4;
        *(float4*)&lds[OFF_WCAT + k * WCAT_S + 64 + c4] = *(const float4*)(E1 + (size_t)(64 + k) * D4 + c4);
    }
#pragma unroll
    for (int i = 0; i < 2; ++i) {  // S1 rows 0..63 -> cols [128,160)
        const int f = t + 256 * i; const int k = f >> 3, c4 = (f & 7) * 4;
        *(float4*)&lds[OFF_WCAT + k * WCAT_S + 128 + c4] = *(const float4*)(S1 + (size_t)k * 32 + c4);
    }
#pragma unroll
    for (int i = 0; i < 2; ++i) {  // S1 rows 64..127 -> cols [160,192)
        const int f = t + 256 * i; const int k = f >> 3, c4 = (f & 7) * 4;
        *(float4*)&lds[OFF_WCAT + k * WCAT_S + 160 + c4] = *(const float4*)(S1 + (size_t)(64 + k) * 32 + c4);
    }

    // ---- phase 4: LayerNorm per row (two-pass, matches reference) ----
    {
        const int r4 = t >> 2, q = t & 3;   // 4 lanes per row, 16 cols each
        float vb[16];
        float s = 0.f;
#pragma unroll
        for (int d = 0; d < 4; ++d) {
            const float4 v = *(const float4*)&lds[OFF_HS + r4 * HS_S + 16 * q + 4 * d];
            vb[4*d+0] = v.x; vb[4*d+1] = v.y; vb[4*d+2] = v.z; vb[4*d+3] = v.w;
            s += v.x + v.y + v.z + v.w;
        }
        s += __shfl_xor(s, 1); s += __shfl_xor(s, 2);
        const float mu = s * (1.0f / 64.0f);
        float vs = 0.f;
#pragma unroll
        for (int e = 0; e < 16; ++e) { const float dd = vb[e] - mu; vs = fmaf(dd, dd, vs); }
        vs += __shfl_xor(vs, 1); vs += __shfl_xor(vs, 2);
        const float rstd = rsqrtf(vs * (1.0f / 64.0f) + 1e-5f);
#pragma unroll
        for (int d = 0; d < 4; ++d) {
            const float4 gv = *(const float4*)(gamma + 16 * q + 4 * d);
            const float4 bv = *(const float4*)(beta  + 16 * q + 4 * d);
            float4 o;
            o.x = fmaf((vb[4*d+0] - mu) * rstd, gv.x, bv.x);
            o.y = fmaf((vb[4*d+1] - mu) * rstd, gv.y, bv.y);
            o.z = fmaf((vb[4*d+2] - mu) * rstd, gv.z, bv.z);
            o.w = fmaf((vb[4*d+3] - mu) * rstd, gv.w, bv.w);
            *(float4*)(out_nf + (size_t)b * 4096 + (size_t)r4 * 64 + 16 * q + 4 * d) = o;
            // transposed copy for phase 5
            lds[OFF_NFS + (16*q + 4*d + 0) * NF_S + r4] = o.x;
            lds[OFF_NFS + (16*q + 4*d + 1) * NF_S + r4] = o.y;
            lds[OFF_NFS + (16*q + 4*d + 2) * NF_S + r4] = o.z;
            lds[OFF_NFS + (16*q + 4*d + 3) * NF_S + r4] = o.w;
        }
    }
    __syncthreads();

    // ---- phase 5: [ei|ej|si|sj] = nf @ Wcat  (64 x 192, K=64) ----
    float a5[8][6];
#pragma unroll
    for (int r = 0; r < 8; ++r)
#pragma unroll
        for (int c = 0; c < 6; ++c) a5[r][c] = 0.f;
    const int c5 = 48 * w + 6 * m;
    for (int kk = 0; kk < 64; ++kk) {
        const float4 na = *(const float4*)&lds[OFF_NFS + kk * NF_S + 8 * g];
        const float4 nb = *(const float4*)&lds[OFF_NFS + kk * NF_S + 8 * g + 4];
        const float2 w01 = *(const float2*)&lds[OFF_WCAT + kk * WCAT_S + c5];
        const float2 w23 = *(const float2*)&lds[OFF_WCAT + kk * WCAT_S + c5 + 2];
        const float2 w45 = *(const float2*)&lds[OFF_WCAT + kk * WCAT_S + c5 + 4];
        const float nr[8] = {na.x, na.y, na.z, na.w, nb.x, nb.y, nb.z, nb.w};
        const float wr[6] = {w01.x, w01.y, w23.x, w23.y, w45.x, w45.y};
#pragma unroll
        for (int r = 0; r < 8; ++r)
#pragma unroll
            for (int c = 0; c < 6; ++c)
                a5[r][c] = fmaf(nr[r], wr[c], a5[r][c]);
    }
    // scatter to workspace
#pragma unroll
    for (int cc = 0; cc < 6; ++cc) {
        const int c = c5 + cc;
        float* dst;
        int rs;
        if (c < 64)       { dst = ws_ei + (size_t)b * 4096 + c;        rs = 64; }
        else if (c < 128) { dst = ws_ej + (size_t)b * 4096 + (c - 64); rs = 64; }
        else if (c < 160) { dst = ws_si + (size_t)b * 2048 + (c - 128); rs = 32; }
        else              { dst = ws_sj + (size_t)b * 2048 + (c - 160); rs = 32; }
#pragma unroll
        for (int r = 0; r < 8; ++r)
            dst[(size_t)(8 * g + r) * rs] = a5[r][cc];
    }
}

// ============================================================================
// Kernel B (round 5): MFMA edge stage + separate VALU strength pass.
// Round-4 post-mortem: launch_bounds(256,4) empirically caps at 64 VGPR ->
// ~50 regs spilled (FETCH 163MB vs 31MB real). Fix: (256,2) (empirically
// 128 VGPR in round 2) + S path moved out of the MFMA body (-28 live regs).
// ============================================================================
typedef __attribute__((ext_vector_type(8))) short short8;
typedef __attribute__((ext_vector_type(4))) float f32x4;

__device__ __forceinline__ short f2bf(float f) {
    unsigned u = __builtin_bit_cast(unsigned, f);
    u += 0x7fffu + ((u >> 16) & 1u);         // RNE (no NaN in this data)
    return (short)(u >> 16);
}

constexpr int EJ_S = 76;
constexpr int EI_S = 68;
constexpr int SJ_S = 36;
constexpr int SI_S = 36;

__global__ __launch_bounds__(256, 2)
void kernelB(const float* __restrict__ ws_ei, const float* __restrict__ ws_ej,
             const float* __restrict__ ws_si, const float* __restrict__ ws_sj,
             const float* __restrict__ bE1, const float* __restrict__ E2,
             const float* __restrict__ bE2, const float* __restrict__ E3,
             const float* __restrict__ bE3, const float* __restrict__ bS1,
             const float* __restrict__ S2, const float* __restrict__ bS2,
             float* __restrict__ out_adj, float* __restrict__ out_str)
{
    __shared__ float ejR[64 * EJ_S];   // ej row-major [j][h]
    __shared__ float eis[16 * EI_S];   // ei rows of this i-strip, bE1 folded
    __shared__ float sjR[64 * SJ_S];   // sj row-major [j][k]
    __shared__ float siR[16 * SI_S];   // si rows, bS1 folded
    __shared__ float bE2s[32], E3s[32], S2s[32];
    // ~35.8 KB -> 4 blocks/CU

    const int t  = threadIdx.x;
    const int qi = blockIdx.x;         // i-strip 0..3 (16 i-rows)
    const int b  = blockIdx.y;         // batch
    const int w  = t >> 6, l = t & 63;
    const int g  = l >> 4, r = l & 15;

    // ---- stage ----
#pragma unroll
    for (int it = 0; it < 16; ++it) {  // ejR: 4096
        const int f = t + 256 * it; const int j = f >> 6, h = f & 63;
        ejR[j * EJ_S + h] = ws_ej[(size_t)b * 4096 + (size_t)j * 64 + h];
    }
#pragma unroll
    for (int it = 0; it < 4; ++it) {   // eis: 1024 (+bE1)
        const int f = t + 256 * it; const int rr = f >> 6, h = f & 63;
        eis[rr * EI_S + h] = ws_ei[(size_t)b * 4096 + (size_t)(qi * 16 + rr) * 64 + h] + bE1[h];
    }
#pragma unroll
    for (int it = 0; it < 8; ++it) {   // sjR: 2048
        const int f = t + 256 * it; const int j = f >> 5, k = f & 31;
        sjR[j * SJ_S + k] = ws_sj[(size_t)b * 2048 + (size_t)j * 32 + k];
    }
#pragma unroll
    for (int it = 0; it < 2; ++it) {   // siR: 512 (+bS1)
        const int f = t + 256 * it; const int rr = f >> 5, k = f & 31;
        siR[rr * SI_S + k] = ws_si[(size_t)b * 2048 + (size_t)(qi * 16 + rr) * 32 + k] + bS1[k];
    }
    if (t < 32)       bE2s[t] = bE2[t];
    else if (t < 64)  E3s[t - 32] = E3[t - 32];
    else if (t < 96)  S2s[t - 64] = S2[t - 64];

    // ---- A-frag preload (registers; E2^T), validated mapping from round 4 ----
    short8 aE00, aE10, aE01, aE11;
#pragma unroll
    for (int e = 0; e < 8; ++e) {
        aE00[e] = f2bf(E2[(size_t)(8 * g + e) * 32 + r]);            // s=0, rt=0
        aE10[e] = f2bf(E2[(size_t)(8 * g + e + 32) * 32 + r]);       // s=1, rt=0
        aE01[e] = f2bf(E2[(size_t)(8 * g + e) * 32 + r + 16]);       // s=0, rt=1
        aE11[e] = f2bf(E2[(size_t)(8 * g + e + 32) * 32 + r + 16]);  // s=1, rt=1
    }
    const float bE3v = bE3[0], bS2v = bS2[0];
    __syncthreads();

    // ---- E pass: per wave, i-rows {4w..4w+3} x j-tiles {0,16,32,48} ----
    for (int jt = 0; jt < 4; ++jt) {
        const int j = (jt << 4) + r;                // this lane's B-column
        const float4 ej00 = *(const float4*)&ejR[j * EJ_S + 8 * g];
        const float4 ej01 = *(const float4*)&ejR[j * EJ_S + 8 * g + 4];
        const float4 ej10 = *(const float4*)&ejR[j * EJ_S + 32 + 8 * g];
        const float4 ej11 = *(const float4*)&ejR[j * EJ_S + 32 + 8 * g + 4];

#pragma unroll
        for (int ii = 0; ii < 4; ++ii) {
            const int il = 4 * w + ii;              // i within strip
            const int ig = qi * 16 + il;            // global i
            const float4 ei00 = *(const float4*)&eis[il * EI_S + 8 * g];
            const float4 ei01 = *(const float4*)&eis[il * EI_S + 8 * g + 4];
            const float4 ei10 = *(const float4*)&eis[il * EI_S + 32 + 8 * g];
            const float4 ei11 = *(const float4*)&eis[il * EI_S + 32 + 8 * g + 4];

            short8 b0, b1;                          // he bf16, k-steps 0/1
            b0[0] = f2bf(fmaxf(ei00.x + ej00.x, 0.f));
            b0[1] = f2bf(fmaxf(ei00.y + ej00.y, 0.f));
            b0[2] = f2bf(fmaxf(ei00.z + ej00.z, 0.f));
            b0[3] = f2bf(fmaxf(ei00.w + ej00.w, 0.f));
            b0[4] = f2bf(fmaxf(ei01.x + ej01.x, 0.f));
            b0[5] = f2bf(fmaxf(ei01.y + ej01.y, 0.f));
            b0[6] = f2bf(fmaxf(ei01.z + ej01.z, 0.f));
            b0[7] = f2bf(fmaxf(ei01.w + ej01.w, 0.f));
            b1[0] = f2bf(fmaxf(ei10.x + ej10.x, 0.f));
            b1[1] = f2bf(fmaxf(ei10.y + ej10.y, 0.f));
            b1[2] = f2bf(fmaxf(ei10.z + ej10.z, 0.f));
            b1[3] = f2bf(fmaxf(ei10.w + ej10.w, 0.f));
            b1[4] = f2bf(fmaxf(ei11.x + ej11.x, 0.f));
            b1[5] = f2bf(fmaxf(ei11.y + ej11.y, 0.f));
            b1[6] = f2bf(fmaxf(ei11.z + ej11.z, 0.f));
            b1[7] = f2bf(fmaxf(ei11.w + ej11.w, 0.f));

            f32x4 acc0 = {0.f, 0.f, 0.f, 0.f};
            f32x4 acc1 = {0.f, 0.f, 0.f, 0.f};
            acc0 = __builtin_amdgcn_mfma_f32_16x16x32_bf16(aE00, b0, acc0, 0, 0, 0);
            acc0 = __builtin_amdgcn_mfma_f32_16x16x32_bf16(aE10, b1, acc0, 0, 0, 0);
            acc1 = __builtin_amdgcn_mfma_f32_16x16x32_bf16(aE01, b0, acc1, 0, 0, 0);
            acc1 = __builtin_amdgcn_mfma_f32_16x16x32_bf16(aE11, b1, acc1, 0, 0, 0);

            // ---- epilogue: lane holds D[kout=4g+q (+16)][col j] ----
            float pe = 0.f;
#pragma unroll
            for (int q = 0; q < 4; ++q) {
                const int k0 = 4 * g + q;
                pe += fmaxf(acc0[q] + bE2s[k0], 0.f) * E3s[k0];
                pe += fmaxf(acc1[q] + bE2s[k0 + 16], 0.f) * E3s[k0 + 16];
            }
            pe += __shfl_xor(pe, 16);
            pe += __shfl_xor(pe, 32);

            if (l < 16) {
                const float z = pe + bE3v;
                const float p = 1.0f / (1.0f + __expf(-z));
                const float av = (j == ig || !(p > 0.3f)) ? 0.f : p;
                out_adj[(size_t)b * 4096 + (size_t)ig * 64 + j] = av;
            }
        }
    }

    // ---- S pass (pure VALU; ~0.4 GFLOP total, never the bottleneck) ----
    {
        const int j = t & 63;
        const int ib = (t >> 6) * 4;               // 4 i-rows per thread
#pragma unroll
        for (int ii = 0; ii < 4; ++ii) {
            const int il = ib + ii;
            const int ig = qi * 16 + il;
            float sacc = 0.f;
#pragma unroll
            for (int k8 = 0; k8 < 8; ++k8) {
                const float4 si4 = *(const float4*)&siR[il * SI_S + 4 * k8];
                const float4 sj4 = *(const float4*)&sjR[j * SJ_S + 4 * k8];
                const float4 s24 = *(const float4*)&S2s[4 * k8];
                sacc = fmaf(fmaxf(si4.x + sj4.x, 0.f), s24.x, sacc);
                sacc = fmaf(fmaxf(si4.y + sj4.y, 0.f), s24.y, sacc);
                sacc = fmaf(fmaxf(si4.z + sj4.z, 0.f), s24.z, sacc);
                sacc = fmaf(fmaxf(si4.w + sj4.w, 0.f), s24.w, sacc);
            }
            const float xs = sacc + bS2v;
            const float e2x = __expf(2.0f * xs);
            const float sv = (j == ig) ? 0.f : (e2x - 1.0f) / (e2x + 1.0f);
            out_str[(size_t)b * 4096 + (size_t)ig * 64 + j] = sv;
        }
    }
}

extern "C" void kernel_launch(void* const* d_in, const int* in_sizes, int n_in,
                              void* d_out, int out_size, void* d_ws, size_t ws_size,
                              hipStream_t stream)
{
    const float* x     = (const float*)d_in[0];
    const float* W1    = (const float*)d_in[1];
    const float* b1    = (const float*)d_in[2];
    const float* W2    = (const float*)d_in[3];
    const float* b2    = (const float*)d_in[4];
    const float* gamma = (const float*)d_in[5];
    const float* beta  = (const float*)d_in[6];
    const float* E1    = (const float*)d_in[7];
    const float* bE1   = (const float*)d_in[8];
    const float* E2    = (const float*)d_in[9];
    const float* bE2   = (const float*)d_in[10];
    const float* E3    = (const float*)d_in[11];
    const float* bE3   = (const float*)d_in[12];
    const float* S1    = (const float*)d_in[13];
    const float* bS1   = (const float*)d_in[14];
    const float* S2    = (const float*)d_in[15];
    const float* bS2   = (const float*)d_in[16];

    float* out     = (float*)d_out;
    float* out_nf  = out;                // 256*64*64
    float* out_adj = out + 1048576;
    float* out_str = out + 2097152;

    float* ws    = (float*)d_ws;
    float* ws_ei = ws;                   // 1048576
    float* ws_ej = ws + 1048576;         // 1048576
    float* ws_si = ws + 2097152;         // 524288
    float* ws_sj = ws + 2621440;         // 524288  (total 12 MB)

    (void)hipFuncSetAttribute((const void*)kernelA,
        hipFuncAttributeMaxDynamicSharedMemorySize, LDS_FLOATS * 4);

    kernelA<<<256, 256, LDS_FLOATS * 4, stream>>>(
        x, W1, b1, W2, b2, gamma, beta, E1, S1,
        out_nf, ws_ei, ws_ej, ws_si, ws_sj);

    kernelB<<<dim3(4, 256), 256, 0, stream>>>(
        ws_ei, ws_ej, ws_si, ws_sj,
        bE1, E2, bE2, E3, bE3, bS1, S2, bS2,
        out_adj, out_str);
}

// Round 6
// 55.467 us; speedup vs baseline: 3.2274x; 1.5352x over previous
//
#include <hip/hip_runtime.h>
#include <math.h>

typedef __attribute__((ext_vector_type(8))) short short8;
typedef __attribute__((ext_vector_type(4))) float f32x4;

__device__ __forceinline__ short f2bf(float f) {
    unsigned u = __builtin_bit_cast(unsigned, f);
    u += 0x7fffu + ((u >> 16) & 1u);         // RNE (no NaN in this data)
    return (short)(u >> 16);
}

// ============================================================================
// Kernel A0: one-time weight transpose + bf16 convert into scratch.
// wT layout (shorts): W1T [128n][256k] @0 | W2T [64n][128k] @32768 |
//                     WcatT [192o][64k] @40960  (Wcat = [E1a|E1b|S1a|S1b])
// ============================================================================
__global__ __launch_bounds__(256)
void kernelA0(const float* __restrict__ W1, const float* __restrict__ W2,
              const float* __restrict__ E1, const float* __restrict__ S1,
              short* __restrict__ wT)
{
    const int tid = blockIdx.x * 256 + threadIdx.x;   // 64*256 = 16384
#pragma unroll
    for (int i = 0; i < 2; ++i) {                     // W1T: 32768 elems
        const int e = tid * 2 + i;
        const int n = e >> 8, k = e & 255;
        wT[e] = f2bf(W1[(size_t)k * 128 + n]);
    }
    if (tid < 8192) {                                 // W2T
        const int n = tid >> 7, k = tid & 127;
        wT[32768 + tid] = f2bf(W2[(size_t)k * 64 + n]);
    }
    if (tid < 12288) {                                // WcatT
        const int o = tid >> 6, k = tid & 63;
        float v;
        if (o < 64)       v = E1[(size_t)k * 64 + o];
        else if (o < 128) v = E1[(size_t)(64 + k) * 64 + (o - 64)];
        else if (o < 160) v = S1[(size_t)k * 32 + (o - 128)];
        else              v = S1[(size_t)(64 + k) * 32 + (o - 160)];
        wT[40960 + tid] = f2bf(v);
    }
}

// ============================================================================
// Kernel A (round 6): full MFMA node path. 256 blocks x 4 waves; wave w owns
// rows 16w..16w+15 through all phases (no barriers; LDS regions wave-private).
// B-fragments read direct from L2 (pre-transposed bf16 weights). LN done
// in-register on the MFMA D layout via 16-lane shfl_xor reductions.
// MFMA lane mapping validated on HW in kernelB (rounds 4/5):
//   A[row=l&15][k=8*(l>>4)+e], B[k=8*(l>>4)+e][col=l&15],
//   D[row=4*(l>>4)+q][col=l&15].
// ============================================================================
constexpr int H1B_S = 144;   // bf16 stride (72 words % 32 == 8 -> g-groups disjoint)
constexpr int NFB_S = 80;

__global__ __launch_bounds__(256)
void kernelAm(const float* __restrict__ x,
              const float* __restrict__ b1, const float* __restrict__ b2,
              const float* __restrict__ gamma, const float* __restrict__ beta,
              const short* __restrict__ wT,
              float* __restrict__ out_nf,
              float* __restrict__ ws_ei, float* __restrict__ ws_ej,
              float* __restrict__ ws_si, float* __restrict__ ws_sj)
{
    __shared__ short h1B[64 * H1B_S];   // 18.4 KB
    __shared__ short nfB[64 * NFB_S];   // 10.2 KB (separate: no cross-wave alias)
    const int t = threadIdx.x, b = blockIdx.x;
    const int w = t >> 6, l = t & 63, g = l >> 4, r = l & 15;
    const short* W1T = wT;
    const short* W2T = wT + 32768;
    const short* WcT = wT + 40960;
    const int rowD = 16 * w + 4 * g;    // D-layout row base (+q)

    // ---- A-frags: gathered X rows -> bf16 registers (32 VGPRs) ----
    const int mrow = 16 * w + r;
    const int srow = (mrow == 63) ? 127 : (int)((float)mrow * (127.0f / 63.0f));
    const float* xrow = x + ((size_t)b * 128 + srow) * 256;
    short8 aX[8];
#pragma unroll
    for (int ks = 0; ks < 8; ++ks) {
        const float4 v0 = *(const float4*)(xrow + 32 * ks + 8 * g);
        const float4 v1 = *(const float4*)(xrow + 32 * ks + 8 * g + 4);
        short8 a;
        a[0] = f2bf(v0.x); a[1] = f2bf(v0.y); a[2] = f2bf(v0.z); a[3] = f2bf(v0.w);
        a[4] = f2bf(v1.x); a[5] = f2bf(v1.y); a[6] = f2bf(v1.z); a[7] = f2bf(v1.w);
        aX[ks] = a;
    }

    // ---- phase 2: h1 = relu(X@W1 + b1), one acc live at a time ----
#pragma unroll
    for (int nt = 0; nt < 8; ++nt) {
        const int n = 16 * nt + r;
        f32x4 acc = {0.f, 0.f, 0.f, 0.f};
#pragma unroll
        for (int ks = 0; ks < 8; ++ks) {
            const short8 bw = *(const short8*)(W1T + (size_t)n * 256 + 32 * ks + 8 * g);
            acc = __builtin_amdgcn_mfma_f32_16x16x32_bf16(aX[ks], bw, acc, 0, 0, 0);
        }
        const float b1v = b1[n];
#pragma unroll
        for (int q = 0; q < 4; ++q)
            h1B[(rowD + q) * H1B_S + n] = f2bf(fmaxf(acc[q] + b1v, 0.f));
    }

    // ---- phase 3: h = h1@W2 + b2 (keep all 4 n-tiles for LN) ----
    short8 ha[4];
#pragma unroll
    for (int ks = 0; ks < 4; ++ks)
        ha[ks] = *(const short8*)(&h1B[mrow * H1B_S + 32 * ks + 8 * g]);
    f32x4 hv[4];
#pragma unroll
    for (int nt = 0; nt < 4; ++nt) {
        const int n = 16 * nt + r;
        f32x4 acc = {0.f, 0.f, 0.f, 0.f};
#pragma unroll
        for (int ks = 0; ks < 4; ++ks) {
            const short8 bw = *(const short8*)(W2T + (size_t)n * 128 + 32 * ks + 8 * g);
            acc = __builtin_amdgcn_mfma_f32_16x16x32_bf16(ha[ks], bw, acc, 0, 0, 0);
        }
        const float b2v = b2[n];
        hv[nt][0] = acc[0] + b2v; hv[nt][1] = acc[1] + b2v;
        hv[nt][2] = acc[2] + b2v; hv[nt][3] = acc[3] + b2v;
    }

    // ---- phase 4: LayerNorm in-register (row = rowD+q; 16 lanes per row) ----
    float mu[4], rstd[4];
#pragma unroll
    for (int q = 0; q < 4; ++q) {
        float s = hv[0][q] + hv[1][q] + hv[2][q] + hv[3][q];
        s += __shfl_xor(s, 1); s += __shfl_xor(s, 2);
        s += __shfl_xor(s, 4); s += __shfl_xor(s, 8);
        mu[q] = s * (1.0f / 64.0f);
        float v = 0.f;
#pragma unroll
        for (int nt = 0; nt < 4; ++nt) { const float d = hv[nt][q] - mu[q]; v = fmaf(d, d, v); }
        v += __shfl_xor(v, 1); v += __shfl_xor(v, 2);
        v += __shfl_xor(v, 4); v += __shfl_xor(v, 8);
        rstd[q] = rsqrtf(v * (1.0f / 64.0f) + 1e-5f);
    }
#pragma unroll
    for (int nt = 0; nt < 4; ++nt) {
        const int n = 16 * nt + r;
        const float gv = gamma[n], bv = beta[n];
#pragma unroll
        for (int q = 0; q < 4; ++q) {
            const float nf = fmaf((hv[nt][q] - mu[q]) * rstd[q], gv, bv);
            out_nf[(size_t)b * 4096 + (size_t)(rowD + q) * 64 + n] = nf;
            nfB[(rowD + q) * NFB_S + n] = f2bf(nf);
        }
    }

    // ---- phase 5: [ei|ej|si|sj] = nf @ Wcat (K=64), one acc live ----
    const short8 na0 = *(const short8*)(&nfB[mrow * NFB_S + 8 * g]);
    const short8 na1 = *(const short8*)(&nfB[mrow * NFB_S + 32 + 8 * g]);
#pragma unroll
    for (int nt = 0; nt < 12; ++nt) {
        const int c = 16 * nt + r;
        const short8 bw0 = *(const short8*)(WcT + (size_t)c * 64 + 8 * g);
        const short8 bw1 = *(const short8*)(WcT + (size_t)c * 64 + 32 + 8 * g);
        f32x4 acc = {0.f, 0.f, 0.f, 0.f};
        acc = __builtin_amdgcn_mfma_f32_16x16x32_bf16(na0, bw0, acc, 0, 0, 0);
        acc = __builtin_amdgcn_mfma_f32_16x16x32_bf16(na1, bw1, acc, 0, 0, 0);
        float* dst; int cc, rs;
        if (nt < 4)       { dst = ws_ei + (size_t)b * 4096; cc = c;       rs = 64; }
        else if (nt < 8)  { dst = ws_ej + (size_t)b * 4096; cc = c - 64;  rs = 64; }
        else if (nt < 10) { dst = ws_si + (size_t)b * 2048; cc = c - 128; rs = 32; }
        else              { dst = ws_sj + (size_t)b * 2048; cc = c - 160; rs = 32; }
#pragma unroll
        for (int q = 0; q < 4; ++q)
            dst[(size_t)(rowD + q) * rs + cc] = acc[q];
    }
}

// ============================================================================
// Kernel B (unchanged from round 5): MFMA edge stage + VALU strength pass.
// ============================================================================
constexpr int EJ_S = 76;
constexpr int EI_S = 68;
constexpr int SJ_S = 36;
constexpr int SI_S = 36;

__global__ __launch_bounds__(256, 2)
void kernelB(const float* __restrict__ ws_ei, const float* __restrict__ ws_ej,
             const float* __restrict__ ws_si, const float* __restrict__ ws_sj,
             const float* __restrict__ bE1, const float* __restrict__ E2,
             const float* __restrict__ bE2, const float* __restrict__ E3,
             const float* __restrict__ bE3, const float* __restrict__ bS1,
             const float* __restrict__ S2, const float* __restrict__ bS2,
             float* __restrict__ out_adj, float* __restrict__ out_str)
{
    __shared__ float ejR[64 * EJ_S];   // ej row-major [j][h]
    __shared__ float eis[16 * EI_S];   // ei rows of this i-strip, bE1 folded
    __shared__ float sjR[64 * SJ_S];   // sj row-major [j][k]
    __shared__ float siR[16 * SI_S];   // si rows, bS1 folded
    __shared__ float bE2s[32], E3s[32], S2s[32];

    const int t  = threadIdx.x;
    const int qi = blockIdx.x;         // i-strip 0..3 (16 i-rows)
    const int b  = blockIdx.y;         // batch
    const int w  = t >> 6, l = t & 63;
    const int g  = l >> 4, r = l & 15;

#pragma unroll
    for (int it = 0; it < 16; ++it) {  // ejR: 4096
        const int f = t + 256 * it; const int j = f >> 6, h = f & 63;
        ejR[j * EJ_S + h] = ws_ej[(size_t)b * 4096 + (size_t)j * 64 + h];
    }
#pragma unroll
    for (int it = 0; it < 4; ++it) {   // eis: 1024 (+bE1)
        const int f = t + 256 * it; const int rr = f >> 6, h = f & 63;
        eis[rr * EI_S + h] = ws_ei[(size_t)b * 4096 + (size_t)(qi * 16 + rr) * 64 + h] + bE1[h];
    }
#pragma unroll
    for (int it = 0; it < 8; ++it) {   // sjR: 2048
        const int f = t + 256 * it; const int j = f >> 5, k = f & 31;
        sjR[j * SJ_S + k] = ws_sj[(size_t)b * 2048 + (size_t)j * 32 + k];
    }
#pragma unroll
    for (int it = 0; it < 2; ++it) {   // siR: 512 (+bS1)
        const int f = t + 256 * it; const int rr = f >> 5, k = f & 31;
        siR[rr * SI_S + k] = ws_si[(size_t)b * 2048 + (size_t)(qi * 16 + rr) * 32 + k] + bS1[k];
    }
    if (t < 32)       bE2s[t] = bE2[t];
    else if (t < 64)  E3s[t - 32] = E3[t - 32];
    else if (t < 96)  S2s[t - 64] = S2[t - 64];

    short8 aE00, aE10, aE01, aE11;
#pragma unroll
    for (int e = 0; e < 8; ++e) {
        aE00[e] = f2bf(E2[(size_t)(8 * g + e) * 32 + r]);
        aE10[e] = f2bf(E2[(size_t)(8 * g + e + 32) * 32 + r]);
        aE01[e] = f2bf(E2[(size_t)(8 * g + e) * 32 + r + 16]);
        aE11[e] = f2bf(E2[(size_t)(8 * g + e + 32) * 32 + r + 16]);
    }
    const float bE3v = bE3[0], bS2v = bS2[0];
    __syncthreads();

    for (int jt = 0; jt < 4; ++jt) {
        const int j = (jt << 4) + r;
        const float4 ej00 = *(const float4*)&ejR[j * EJ_S + 8 * g];
        const float4 ej01 = *(const float4*)&ejR[j * EJ_S + 8 * g + 4];
        const float4 ej10 = *(const float4*)&ejR[j * EJ_S + 32 + 8 * g];
        const float4 ej11 = *(const float4*)&ejR[j * EJ_S + 32 + 8 * g + 4];

#pragma unroll
        for (int ii = 0; ii < 4; ++ii) {
            const int il = 4 * w + ii;
            const int ig = qi * 16 + il;
            const float4 ei00 = *(const float4*)&eis[il * EI_S + 8 * g];
            const float4 ei01 = *(const float4*)&eis[il * EI_S + 8 * g + 4];
            const float4 ei10 = *(const float4*)&eis[il * EI_S + 32 + 8 * g];
            const float4 ei11 = *(const float4*)&eis[il * EI_S + 32 + 8 * g + 4];

            short8 b0, b1v;
            b0[0] = f2bf(fmaxf(ei00.x + ej00.x, 0.f));
            b0[1] = f2bf(fmaxf(ei00.y + ej00.y, 0.f));
            b0[2] = f2bf(fmaxf(ei00.z + ej00.z, 0.f));
            b0[3] = f2bf(fmaxf(ei00.w + ej00.w, 0.f));
            b0[4] = f2bf(fmaxf(ei01.x + ej01.x, 0.f));
            b0[5] = f2bf(fmaxf(ei01.y + ej01.y, 0.f));
            b0[6] = f2bf(fmaxf(ei01.z + ej01.z, 0.f));
            b0[7] = f2bf(fmaxf(ei01.w + ej01.w, 0.f));
            b1v[0] = f2bf(fmaxf(ei10.x + ej10.x, 0.f));
            b1v[1] = f2bf(fmaxf(ei10.y + ej10.y, 0.f));
            b1v[2] = f2bf(fmaxf(ei10.z + ej10.z, 0.f));
            b1v[3] = f2bf(fmaxf(ei10.w + ej10.w, 0.f));
            b1v[4] = f2bf(fmaxf(ei11.x + ej11.x, 0.f));
            b1v[5] = f2bf(fmaxf(ei11.y + ej11.y, 0.f));
            b1v[6] = f2bf(fmaxf(ei11.z + ej11.z, 0.f));
            b1v[7] = f2bf(fmaxf(ei11.w + ej11.w, 0.f));

            f32x4 acc0 = {0.f, 0.f, 0.f, 0.f};
            f32x4 acc1 = {0.f, 0.f, 0.f, 0.f};
            acc0 = __builtin_amdgcn_mfma_f32_16x16x32_bf16(aE00, b0,  acc0, 0, 0, 0);
            acc0 = __builtin_amdgcn_mfma_f32_16x16x32_bf16(aE10, b1v, acc0, 0, 0, 0);
            acc1 = __builtin_amdgcn_mfma_f32_16x16x32_bf16(aE01, b0,  acc1, 0, 0, 0);
            acc1 = __builtin_amdgcn_mfma_f32_16x16x32_bf16(aE11, b1v, acc1, 0, 0, 0);

            float pe = 0.f;
#pragma unroll
            for (int q = 0; q < 4; ++q) {
                const int k0 = 4 * g + q;
                pe += fmaxf(acc0[q] + bE2s[k0], 0.f) * E3s[k0];
                pe += fmaxf(acc1[q] + bE2s[k0 + 16], 0.f) * E3s[k0 + 16];
            }
            pe += __shfl_xor(pe, 16);
            pe += __shfl_xor(pe, 32);

            if (l < 16) {
                const float z = pe + bE3v;
                const float p = 1.0f / (1.0f + __expf(-z));
                const float av = (j == ig || !(p > 0.3f)) ? 0.f : p;
                out_adj[(size_t)b * 4096 + (size_t)ig * 64 + j] = av;
            }
        }
    }

    // ---- S pass (pure VALU) ----
    {
        const int j = t & 63;
        const int ib = (t >> 6) * 4;
#pragma unroll
        for (int ii = 0; ii < 4; ++ii) {
            const int il = ib + ii;
            const int ig = qi * 16 + il;
            float sacc = 0.f;
#pragma unroll
            for (int k8 = 0; k8 < 8; ++k8) {
                const float4 si4 = *(const float4*)&siR[il * SI_S + 4 * k8];
                const float4 sj4 = *(const float4*)&sjR[j * SJ_S + 4 * k8];
                const float4 s24 = *(const float4*)&S2s[4 * k8];
                sacc = fmaf(fmaxf(si4.x + sj4.x, 0.f), s24.x, sacc);
                sacc = fmaf(fmaxf(si4.y + sj4.y, 0.f), s24.y, sacc);
                sacc = fmaf(fmaxf(si4.z + sj4.z, 0.f), s24.z, sacc);
                sacc = fmaf(fmaxf(si4.w + sj4.w, 0.f), s24.w, sacc);
            }
            const float xs = sacc + bS2v;
            const float e2x = __expf(2.0f * xs);
            const float sv = (j == ig) ? 0.f : (e2x - 1.0f) / (e2x + 1.0f);
            out_str[(size_t)b * 4096 + (size_t)ig * 64 + j] = sv;
        }
    }
}

extern "C" void kernel_launch(void* const* d_in, const int* in_sizes, int n_in,
                              void* d_out, int out_size, void* d_ws, size_t ws_size,
                              hipStream_t stream)
{
    const float* x     = (const float*)d_in[0];
    const float* W1    = (const float*)d_in[1];
    const float* b1    = (const float*)d_in[2];
    const float* W2    = (const float*)d_in[3];
    const float* b2    = (const float*)d_in[4];
    const float* gamma = (const float*)d_in[5];
    const float* beta  = (const float*)d_in[6];
    const float* E1    = (const float*)d_in[7];
    const float* bE1   = (const float*)d_in[8];
    const float* E2    = (const float*)d_in[9];
    const float* bE2   = (const float*)d_in[10];
    const float* E3    = (const float*)d_in[11];
    const float* bE3   = (const float*)d_in[12];
    const float* S1    = (const float*)d_in[13];
    const float* bS1   = (const float*)d_in[14];
    const float* S2    = (const float*)d_in[15];
    const float* bS2   = (const float*)d_in[16];

    float* out     = (float*)d_out;
    float* out_nf  = out;                // 256*64*64
    float* out_adj = out + 1048576;
    float* out_str = out + 2097152;

    float* ws    = (float*)d_ws;
    float* ws_ei = ws;                   // 1048576
    float* ws_ej = ws + 1048576;         // 1048576
    float* ws_si = ws + 2097152;         // 524288
    float* ws_sj = ws + 2621440;         // 524288  (total 12 MB)

    // Transposed bf16 weights live in the out_str region: written by A0,
    // read by Am, fully overwritten by B afterwards (single-stream ordering).
    short* wT = (short*)out_str;         // 53248 shorts = 104 KB << 4 MB

    kernelA0<<<64, 256, 0, stream>>>(W1, W2, E1, S1, wT);

    kernelAm<<<256, 256, 0, stream>>>(
        x, b1, b2, gamma, beta, wT,
        out_nf, ws_ei, ws_ej, ws_si, ws_sj);

    kernelB<<<dim3(4, 256), 256, 0, stream>>>(
        ws_ei, ws_ej, ws_si, ws_sj,
        bE1, E2, bE2, E3, bE3, bS1, S2, bS2,
        out_adj, out_str);
}